// Round 11
// baseline (248.581 us; speedup 1.0000x reference)
//
#include <hip/hip_runtime.h>

#define N_SEQ 1024
#define B_SZ 8
#define C_DIM 256
#define K_HEADS 4
#define FF_DIM 2048

typedef short s16x8 __attribute__((ext_vector_type(8)));
typedef float f32x4v __attribute__((ext_vector_type(4)));

#define GLOAD_LDS16(src, dst)                                                              \
    __builtin_amdgcn_global_load_lds((const __attribute__((address_space(1))) void*)(src), \
                                     (__attribute__((address_space(3))) void*)(dst), 16, 0, 0)

__device__ __forceinline__ unsigned short f2bf(float f) {
    unsigned u = __builtin_bit_cast(unsigned, f);
    u += 0x7FFFu + ((u >> 16) & 1u);
    return (unsigned short)(u >> 16);
}
__device__ __forceinline__ float bf2f(unsigned short h) {
    unsigned u = ((unsigned)h) << 16;
    return __builtin_bit_cast(float, u);
}

// ---------------- prep kernels ----------------

__global__ __launch_bounds__(256) void prep_q_kernel(const float* __restrict__ src,
                                                     const float* __restrict__ pos,
                                                     unsigned short* __restrict__ qb) {
    int t = blockIdx.x * 256 + threadIdx.x;
    int i4 = t * 4;
    float4 s = *reinterpret_cast<const float4*>(src + i4);
    float4 p = *reinterpret_cast<const float4*>(pos + i4);
    int n = i4 >> 11;
    int rem = i4 & 2047;
    int b = rem >> 8;
    int c = rem & 255;
    int out = (b * N_SEQ + n) * C_DIM + c;
    *reinterpret_cast<ushort4*>(qb + out) = make_ushort4(
        f2bf((s.x + p.x) * 0.0625f), f2bf((s.y + p.y) * 0.0625f),
        f2bf((s.z + p.z) * 0.0625f), f2bf((s.w + p.w) * 0.0625f));
}

// One block per (k,b,ntile of 64): writes kb row-major (+pos) and V in
// per-wave-linear fragment order: vfrag[pr][tile32][ct=16][lane=64][e=8].
__global__ __launch_bounds__(256) void prep_kv_kernel(const float* __restrict__ matched,
                                                      const float* __restrict__ pos,
                                                      unsigned short* __restrict__ kb,
                                                      unsigned short* __restrict__ vfrag) {
    __shared__ unsigned short Vl[64][256];
    int blk = blockIdx.x;
    int nt = blk & 15, pr = blk >> 4;          // pr = k*8+b
    int k = pr >> 3, b = pr & 7;
    int n0 = nt * 64;
    int t = threadIdx.x;
    int c4 = (t & 63) * 4;
#pragma unroll
    for (int r = 0; r < 16; r++) {
        int nl = (t >> 6) * 16 + r;
        int n = n0 + nl;
        size_t mi = ((size_t)(k * N_SEQ + n) * B_SZ + b) * C_DIM + c4;
        float4 m = *reinterpret_cast<const float4*>(matched + mi);
        float4 p = *reinterpret_cast<const float4*>(pos + ((size_t)n * B_SZ + b) * C_DIM + c4);
        *reinterpret_cast<ushort4*>(kb + ((size_t)pr * N_SEQ + n) * C_DIM + c4) =
            make_ushort4(f2bf(m.x + p.x), f2bf(m.y + p.y), f2bf(m.z + p.z), f2bf(m.w + p.w));
        *reinterpret_cast<ushort4*>(&Vl[nl][c4]) =
            make_ushort4(f2bf(m.x), f2bf(m.y), f2bf(m.z), f2bf(m.w));
    }
    __syncthreads();
#pragma unroll
    for (int h = 0; h < 2; h++) {
        unsigned short* tb = vfrag + ((size_t)(pr * 32 + nt * 2 + h)) * 8192;
#pragma unroll
        for (int g = 0; g < 4; g++) {
            int c2 = t + 256 * g;                // chunk index 0..1023
            int ct = c2 >> 6;
            int lane2 = c2 & 63;
            int l152 = lane2 & 15, lg2 = lane2 >> 4;
            s16x8 v;
#pragma unroll
            for (int e = 0; e < 8; e++)
                v[e] = (short)Vl[h * 32 + lg2 * 8 + e][ct * 16 + l152];
            *reinterpret_cast<s16x8*>(tb + (size_t)c2 * 8) = v;
        }
    }
}

// merged weight transposes: Wt[c*R+r] = bf16(W[r*Cn+c]); all R,Cn powers of 2
__global__ __launch_bounds__(256) void transpose_all_kernel(const float* __restrict__ Wagg,
                                                            const float* __restrict__ W1,
                                                            const float* __restrict__ W2,
                                                            unsigned short* __restrict__ WaggT,
                                                            unsigned short* __restrict__ W1T,
                                                            unsigned short* __restrict__ W2T) {
    int idx = blockIdx.x * 256 + threadIdx.x;
    if (idx < 262144) {                        // Wagg: R=1024, Cn=256
        int c = idx >> 10, r = idx & 1023;
        WaggT[idx] = f2bf(Wagg[(size_t)r * 256 + c]);
    } else if (idx < 786432) {                 // W1: R=256, Cn=2048
        int i = idx - 262144;
        int c = i >> 8, r = i & 255;
        W1T[i] = f2bf(W1[(size_t)r * 2048 + c]);
    } else {                                   // W2: R=2048, Cn=256
        int i = idx - 786432;
        int c = i >> 11, r = i & 2047;
        W2T[i] = f2bf(W2[(size_t)r * 256 + c]);
    }
}

// ---------------- flash attention (KV-split x2, cooperative ch-split PV) ----------------
// grid = 1024 blocks x 256 threads. Block = 64 q (4 waves) x half the KV range.
// Wave w: QK+softmax for q-tile w; PV for channel quarter of ALL 4 q-tiles.
// LDS 37.5 KB -> 4 blocks/CU.
__global__ __launch_bounds__(256, 4) void attn_kernel(const unsigned short* __restrict__ qb,
                                                      const unsigned short* __restrict__ kb,
                                                      const unsigned short* __restrict__ vfrag,
                                                      const float* __restrict__ mask,
                                                      unsigned short* __restrict__ op0,
                                                      unsigned short* __restrict__ op1,
                                                      float2* __restrict__ mlb) {
    __shared__ unsigned short Kl[2][8192];       // 32 KB: K tile, XOR-swizzled content
    __shared__ unsigned short Psh[4][16][40];    // 5 KB: P exchange (single buffer: barrier A
                                                 //   separates PV-reads(t) from publish(t+1))
    __shared__ float scl[4][17];                 // rescale factors
    __shared__ float lrex[4][17];                // final l exchange

    int bx = blockIdx.x;
    int b = bx & 7;                              // XCD owns one batch's mask/Q
    int r2 = bx >> 3;
    int half = r2 & 1;
    int kidx = (r2 >> 1) & 3;
    int qtb = r2 >> 3;                           // 0..15 (64-q tiles)
    int pr = kidx * 8 + b;

    int tid = threadIdx.x, wid = tid >> 6, lane = tid & 63;
    int l15 = lane & 15, lg = lane >> 4;
    int q0 = qtb * 64 + wid * 16;                // wave's own q-tile base
    int kvh = half * 512;

    // Q fragments (wave's own 16 q)
    s16x8 qf[8];
    const unsigned short* qrow = qb + ((size_t)(b * N_SEQ + q0 + l15)) * C_DIM + lg * 8;
#pragma unroll
    for (int cc = 0; cc < 8; cc++) qf[cc] = *reinterpret_cast<const s16x8*>(qrow + cc * 32);

    f32x4v oacc[16];
#pragma unroll
    for (int i = 0; i < 16; i++) oacc[i] = (f32x4v){0.f, 0.f, 0.f, 0.f};
    float mrun = -3e38f, lrun = 0.f;

    const unsigned short* kbp = kb + ((size_t)pr * N_SEQ + kvh) * C_DIM;
    const unsigned short* vfp = vfrag + ((size_t)(pr * 32 + half * 16)) * 8192 + lane * 8;
    const float* mrow = mask + ((size_t)b * N_SEQ + q0 + l15) * N_SEQ + kvh;

    auto stage_k = [&](int kv0, unsigned short* buf) {
#pragma unroll
        for (int i = 0; i < 4; i++) {
            int ch = (wid * 4 + i) * 64 + lane;
            int r = ch >> 5;
            int ce = ((ch & 31) * 8) ^ ((r & 7) << 3);
            GLOAD_LDS16(kbp + (size_t)(kv0 + r) * C_DIM + ce, &buf[(wid * 4 + i) * 512]);
        }
    };

    // prologue
    stage_k(0, &Kl[0][0]);
    f32x4v mc0 = *reinterpret_cast<const f32x4v*>(mrow + lg * 4);
    f32x4v mc1 = *reinterpret_cast<const f32x4v*>(mrow + 16 + lg * 4);

    int swz = (l15 & 7) << 3;
    for (int t = 0; t < 16; t++) {
        int cur = t & 1;
        int kv0 = t * 32;
        __syncthreads();                         // (A) K[t] ready; Psh free (PV(t-1) done)
        if (t + 1 < 16) stage_k(kv0 + 32, &Kl[cur ^ 1][0]);

        // V fragments for this wave's channel quarter (4 coalesced 1KB loads, L2)
        const unsigned short* vsrc = vfp + (size_t)t * 8192;
        s16x8 vreg[4];
#pragma unroll
        for (int c = 0; c < 4; c++)
            vreg[c] = *reinterpret_cast<const s16x8*>(vsrc + (wid * 4 + c) * 512);

        // S^T = K Q^T (own q-tile)
        f32x4v s0 = {0.f, 0.f, 0.f, 0.f}, s1 = {0.f, 0.f, 0.f, 0.f};
        const unsigned short* KlB = &Kl[cur][0];
        __builtin_amdgcn_s_setprio(1);
#pragma unroll
        for (int cc = 0; cc < 8; cc++) {
            s16x8 k0 = *reinterpret_cast<const s16x8*>(KlB + l15 * 256 + ((cc * 32 + lg * 8) ^ swz));
            s16x8 k1 = *reinterpret_cast<const s16x8*>(KlB + (16 + l15) * 256 + ((cc * 32 + lg * 8) ^ swz));
            s0 = __builtin_amdgcn_mfma_f32_16x16x32_bf16(k0, qf[cc], s0, 0, 0, 0);
            s1 = __builtin_amdgcn_mfma_f32_16x16x32_bf16(k1, qf[cc], s1, 0, 0, 0);
        }
        __builtin_amdgcn_s_setprio(0);
#pragma unroll
        for (int jj = 0; jj < 4; jj++) { s0[jj] += mc0[jj]; s1[jj] += mc1[jj]; }
        if (t + 1 < 16) {
            mc0 = *reinterpret_cast<const f32x4v*>(mrow + kv0 + 32 + lg * 4);
            mc1 = *reinterpret_cast<const f32x4v*>(mrow + kv0 + 48 + lg * 4);
        }

        // online softmax over kv (in-lane 8 + xor 16/32)
        float pm = fmaxf(fmaxf(fmaxf(s0[0], s0[1]), fmaxf(s0[2], s0[3])),
                         fmaxf(fmaxf(s1[0], s1[1]), fmaxf(s1[2], s1[3])));
        pm = fmaxf(pm, __shfl_xor(pm, 16));
        pm = fmaxf(pm, __shfl_xor(pm, 32));
        float sc = 1.0f;
        if (__any(pm > mrun + 8.f)) {            // defer-max
            float mn = fmaxf(mrun, pm);
            sc = __expf(mrun - mn);
            mrun = mn;
        }
        float p0[4], p1[4];
#pragma unroll
        for (int jj = 0; jj < 4; jj++) {
            p0[jj] = __expf(s0[jj] - mrun);
            p1[jj] = __expf(s1[jj] - mrun);
        }
        float ps = (p0[0] + p0[1]) + (p0[2] + p0[3]) + (p1[0] + p1[1]) + (p1[2] + p1[3]);
        ps += __shfl_xor(ps, 16);
        ps += __shfl_xor(ps, 32);
        lrun = lrun * sc + ps;

        // publish P (A-fragment layout) + rescale factor
        *reinterpret_cast<ushort4*>(&Psh[wid][l15][lg * 4]) =
            make_ushort4(f2bf(p0[0]), f2bf(p0[1]), f2bf(p0[2]), f2bf(p0[3]));
        *reinterpret_cast<ushort4*>(&Psh[wid][l15][16 + lg * 4]) =
            make_ushort4(f2bf(p1[0]), f2bf(p1[1]), f2bf(p1[2]), f2bf(p1[3]));
        if (lane < 16) scl[wid][lane] = sc;
        __syncthreads();                         // (B) P + sc visible

        // PV: this wave's 64 channels x all 4 q-tiles
        __builtin_amdgcn_s_setprio(1);
#pragma unroll
        for (int j = 0; j < 4; j++) {
            float scj = scl[j][l15];
            s16x8 pf = *reinterpret_cast<const s16x8*>(&Psh[j][l15][lg * 8]);
            if (__any(scj != 1.0f)) {            // wave-uniform: rescale only when needed
#pragma unroll
                for (int c = 0; c < 4; c++)
#pragma unroll
                    for (int jj = 0; jj < 4; jj++) oacc[j * 4 + c][jj] *= scj;
            }
#pragma unroll
            for (int c = 0; c < 4; c++) {
                int idx = j * 4 + c;
                oacc[idx] = __builtin_amdgcn_mfma_f32_16x16x32_bf16(vreg[c], pf, oacc[idx], 0, 0, 0);
            }
        }
        __builtin_amdgcn_s_setprio(0);
    }

    // epilogue: exchange l, normalize, write partial O + (m,l)
    if (lane < 16) lrex[wid][lane] = lrun;
    __syncthreads();
    unsigned short* Op = half ? op1 : op0;
#pragma unroll
    for (int j = 0; j < 4; j++) {
        float invj = 1.0f / lrex[j][l15];
#pragma unroll
        for (int c = 0; c < 4; c++) {
            int idx = j * 4 + c;
            size_t orow = ((size_t)(b * N_SEQ + qtb * 64 + j * 16 + l15)) * (K_HEADS * C_DIM)
                          + kidx * C_DIM + wid * 64 + c * 16 + lg * 4;
            *reinterpret_cast<ushort4*>(Op + orow) =
                make_ushort4(f2bf(oacc[idx][0] * invj), f2bf(oacc[idx][1] * invj),
                             f2bf(oacc[idx][2] * invj), f2bf(oacc[idx][3] * invj));
        }
    }
    if (lg == 0)
        mlb[((size_t)(half * 4 + kidx) * 8 + b) * N_SEQ + q0 + l15] = make_float2(mrun, lrun);
}

// ---------------- combine two KV-half partials ----------------
__global__ __launch_bounds__(256) void combine_kernel(const unsigned short* __restrict__ op0,
                                                      const unsigned short* __restrict__ op1,
                                                      const float2* __restrict__ mlb,
                                                      unsigned short* __restrict__ att) {
    int t = blockIdx.x * 256 + threadIdx.x;
    int kidx = (t >> 5) & 3;
    int bn = t >> 7;
    int n = bn & 1023, b = bn >> 10;
    float2 e0 = mlb[((size_t)kidx * 8 + b) * N_SEQ + n];
    float2 e1 = mlb[((size_t)(4 + kidx) * 8 + b) * N_SEQ + n];
    float M = fmaxf(e0.x, e1.x);
    float w0 = e0.y * __expf(e0.x - M);
    float w1 = e1.y * __expf(e1.x - M);
    float r = 1.0f / (w0 + w1);
    w0 *= r;
    w1 *= r;
    s16x8 a = *reinterpret_cast<const s16x8*>(op0 + (size_t)t * 8);
    s16x8 c = *reinterpret_cast<const s16x8*>(op1 + (size_t)t * 8);
    s16x8 o;
#pragma unroll
    for (int i = 0; i < 8; i++)
        o[i] = (short)f2bf(w0 * bf2f((unsigned short)a[i]) + w1 * bf2f((unsigned short)c[i]));
    *reinterpret_cast<s16x8*>(att + (size_t)t * 8) = o;
}

// ---------------- GEMM: C = A(MxK) * Bt(NxK)^T + bias, optional split-K ----------------
template <int BM, int BN, int RELU, int OUTBF, int SPLITK>
__global__ __launch_bounds__(256) void gemm_bt_kernel(const unsigned short* __restrict__ A,
                                                      const unsigned short* __restrict__ Bt,
                                                      const float* __restrict__ bias,
                                                      float* __restrict__ Cf0,
                                                      float* __restrict__ Cf1,
                                                      unsigned short* __restrict__ Cb,
                                                      int M, int Nn, int Kd) {
    constexpr int WAVES_N = (BM == 128) ? 2 : 4;
    constexpr int WN = BN / WAVES_N;
    constexpr int NT = WN / 16;
    constexpr int TILE = (BM + BN) * 64;
    constexpr int CALLS = (BM + BN) / 32;
    __shared__ unsigned short Sl[2][TILE];
    int tm0 = blockIdx.y * BM, tn0 = blockIdx.x * BN;
    int kz = (SPLITK == 2) ? blockIdx.z : 0;
    int kbase = kz * (Kd / SPLITK);
    int tid = threadIdx.x, wid = tid >> 6, lane = tid & 63;
    int l15 = lane & 15, lg = lane >> 4;
    int wm = (wid / WAVES_N) * 64, wn = (wid % WAVES_N) * WN;

    f32x4v acc[4][NT];
#pragma unroll
    for (int i = 0; i < 4; i++)
#pragma unroll
        for (int j = 0; j < NT; j++) acc[i][j] = (f32x4v){0.f, 0.f, 0.f, 0.f};

    auto stage = [&](int k0, unsigned short* buf) {
#pragma unroll
        for (int i = 0; i < CALLS; i++) {
            int chb = (i * 4 + wid) * 64;
            int ch = chb + lane;
            const unsigned short* src;
            if (chb < BM * 8) {
                int r = ch >> 3;
                int c8 = ((ch & 7) * 8) ^ ((r & 7) << 3);
                src = A + (size_t)(tm0 + r) * Kd + k0 + c8;
            } else {
                int ch2 = ch - BM * 8;
                int r = ch2 >> 3;
                int c8 = ((ch2 & 7) * 8) ^ ((r & 7) << 3);
                src = Bt + (size_t)(tn0 + r) * Kd + k0 + c8;
            }
            GLOAD_LDS16(src, buf + chb * 8);
        }
    };

    stage(kbase, &Sl[0][0]);
    int nk = (Kd / SPLITK) >> 6;
    int swz = (l15 & 7) << 3;
    for (int kt = 0; kt < nk; kt++) {
        int cur = kt & 1;
        __syncthreads();
        if (kt + 1 < nk) stage(kbase + (kt + 1) * 64, &Sl[cur ^ 1][0]);
        const unsigned short* SA = &Sl[cur][0];
        const unsigned short* SB = SA + BM * 64;
        s16x8 af[4][2], bf[NT][2];
#pragma unroll
        for (int mt = 0; mt < 4; mt++)
#pragma unroll
            for (int h = 0; h < 2; h++)
                af[mt][h] = *reinterpret_cast<const s16x8*>(
                    SA + (wm + mt * 16 + l15) * 64 + ((h * 32 + lg * 8) ^ swz));
#pragma unroll
        for (int nt = 0; nt < NT; nt++)
#pragma unroll
            for (int h = 0; h < 2; h++)
                bf[nt][h] = *reinterpret_cast<const s16x8*>(
                    SB + (wn + nt * 16 + l15) * 64 + ((h * 32 + lg * 8) ^ swz));
        __builtin_amdgcn_s_setprio(1);
#pragma unroll
        for (int mt = 0; mt < 4; mt++)
#pragma unroll
            for (int nt = 0; nt < NT; nt++) {
                acc[mt][nt] = __builtin_amdgcn_mfma_f32_16x16x32_bf16(af[mt][0], bf[nt][0], acc[mt][nt], 0, 0, 0);
                acc[mt][nt] = __builtin_amdgcn_mfma_f32_16x16x32_bf16(af[mt][1], bf[nt][1], acc[mt][nt], 0, 0, 0);
            }
        __builtin_amdgcn_s_setprio(0);
    }

    float* Cf = (SPLITK == 2 && kz) ? Cf1 : Cf0;
#pragma unroll
    for (int mt = 0; mt < 4; mt++) {
#pragma unroll
        for (int nt = 0; nt < NT; nt++) {
#pragma unroll
            for (int j = 0; j < 4; j++) {
                int row = tm0 + wm + mt * 16 + lg * 4 + j;
                int col = tn0 + wn + nt * 16 + l15;
                float bv = (SPLITK == 2 && kz) ? 0.f : bias[col];
                float v = acc[mt][nt][j] + bv;
                if (RELU) v = fmaxf(v, 0.f);
                if (OUTBF) Cb[(size_t)row * Nn + col] = f2bf(v);
                else       Cf[(size_t)row * Nn + col] = v;
            }
        }
    }
}

// ---------------- fused residual + LayerNorm ----------------
__global__ __launch_bounds__(256) void ln1_kernel(const float* __restrict__ src,
                                                  const float* __restrict__ p0,
                                                  const float* __restrict__ p1,
                                                  const float* __restrict__ g,
                                                  const float* __restrict__ be,
                                                  unsigned short* __restrict__ outb) {
    int r = blockIdx.x * 4 + (threadIdx.x >> 6);
    int lane = threadIdx.x & 63;
    int n = r >> 3, b = r & 7;
    int c = lane * 4;
    size_t tb_ = ((size_t)(b * N_SEQ + n)) * C_DIM + c;
    float4 xs = *reinterpret_cast<const float4*>(src + (size_t)r * C_DIM + c);
    float4 xa = *reinterpret_cast<const float4*>(p0 + tb_);
    float4 xb = *reinterpret_cast<const float4*>(p1 + tb_);
    float x[4] = {xs.x + xa.x + xb.x, xs.y + xa.y + xb.y,
                  xs.z + xa.z + xb.z, xs.w + xa.w + xb.w};
    float s = x[0] + x[1] + x[2] + x[3];
    float q = x[0] * x[0] + x[1] * x[1] + x[2] * x[2] + x[3] * x[3];
#pragma unroll
    for (int d = 1; d < 64; d <<= 1) {
        s += __shfl_xor(s, d);
        q += __shfl_xor(q, d);
    }
    float mean = s * (1.f / 256.f);
    float var = q * (1.f / 256.f) - mean * mean;
    float rstd = rsqrtf(var + 1e-5f);
    float4 gv = *reinterpret_cast<const float4*>(g + c);
    float4 bv = *reinterpret_cast<const float4*>(be + c);
    *reinterpret_cast<ushort4*>(outb + (size_t)r * C_DIM + c) = make_ushort4(
        f2bf((x[0] - mean) * rstd * gv.x + bv.x), f2bf((x[1] - mean) * rstd * gv.y + bv.y),
        f2bf((x[2] - mean) * rstd * gv.z + bv.z), f2bf((x[3] - mean) * rstd * gv.w + bv.w));
}

__global__ __launch_bounds__(256) void ln2_kernel(const unsigned short* __restrict__ rec1b,
                                                  const float* __restrict__ p0,
                                                  const float* __restrict__ p1,
                                                  const float* __restrict__ g,
                                                  const float* __restrict__ be,
                                                  float* __restrict__ out) {
    int r = blockIdx.x * 4 + (threadIdx.x >> 6);
    int lane = threadIdx.x & 63;
    int c = lane * 4;
    size_t base = (size_t)r * C_DIM + c;
    ushort4 xr = *reinterpret_cast<const ushort4*>(rec1b + base);
    float4 xa = *reinterpret_cast<const float4*>(p0 + base);
    float4 xb = *reinterpret_cast<const float4*>(p1 + base);
    float x[4] = {bf2f(xr.x) + xa.x + xb.x, bf2f(xr.y) + xa.y + xb.y,
                  bf2f(xr.z) + xa.z + xb.z, bf2f(xr.w) + xa.w + xb.w};
    float s = x[0] + x[1] + x[2] + x[3];
    float q = x[0] * x[0] + x[1] * x[1] + x[2] * x[2] + x[3] * x[3];
#pragma unroll
    for (int d = 1; d < 64; d <<= 1) {
        s += __shfl_xor(s, d);
        q += __shfl_xor(q, d);
    }
    float mean = s * (1.f / 256.f);
    float var = q * (1.f / 256.f) - mean * mean;
    float rstd = rsqrtf(var + 1e-5f);
    float4 gv = *reinterpret_cast<const float4*>(g + c);
    float4 bv = *reinterpret_cast<const float4*>(be + c);
    *reinterpret_cast<float4*>(out + base) = make_float4(
        (x[0] - mean) * rstd * gv.x + bv.x,
        (x[1] - mean) * rstd * gv.y + bv.y,
        (x[2] - mean) * rstd * gv.z + bv.z,
        (x[3] - mean) * rstd * gv.w + bv.w);
}

// ---------------- launch ----------------

extern "C" void kernel_launch(void* const* d_in, const int* in_sizes, int n_in,
                              void* d_out, int out_size, void* d_ws, size_t ws_size,
                              hipStream_t stream) {
    const float* src   = (const float*)d_in[0];
    const float* match = (const float*)d_in[1];
    const float* pos   = (const float*)d_in[2];
    const float* mask  = (const float*)d_in[3];
    const float* Wagg  = (const float*)d_in[4];
    const float* bagg  = (const float*)d_in[5];
    const float* W1    = (const float*)d_in[6];
    const float* b1    = (const float*)d_in[7];
    const float* W2    = (const float*)d_in[8];
    const float* b2    = (const float*)d_in[9];
    const float* g1    = (const float*)d_in[10];
    const float* be1   = (const float*)d_in[11];
    const float* g2    = (const float*)d_in[12];
    const float* be2   = (const float*)d_in[13];

    char* ws = (char*)d_ws;
    unsigned short* qb    = (unsigned short*)(ws + 0);          //  4 MB (prep->attn)
    unsigned short* kb    = (unsigned short*)(ws + 4194304);    // 16 MB (prep->attn)
    unsigned short* vfrag = (unsigned short*)(ws + 20971520);   // 16 MB (prep->attn)
    unsigned short* att   = (unsigned short*)(ws + 37748736);   // 16 MB (attn->gemm1); = op0
    unsigned short* WaggT = (unsigned short*)(ws + 54525952);   // 0.5 MB
    unsigned short* W1T   = (unsigned short*)(ws + 55050240);   // 1 MB
    unsigned short* W2T   = (unsigned short*)(ws + 56098816);   // 1 MB
    float*          rec_p0 = (float*)(ws + 57147392);           // 8 MB (gemm1->ln1)
    float*          rec_p1 = (float*)(ws + 65536000);           // 8 MB (gemm1->ln1)
    // attention-phase aliases (dead regions during attn):
    unsigned short* op0   = att;                                // 16 MB partial half0 (combined in-place)
    unsigned short* op1   = (unsigned short*)(ws + 57147392);   // 16 MB partial half1 (over rec_p0+p1)
    float2*         mlb   = (float2*)(ws + 73924608);           // 512 KB
    // post-attn aliases:
    unsigned short* rec1b = (unsigned short*)(ws + 0);          // 4 MB over qb (ln1->ln2)
    unsigned short* hid   = (unsigned short*)(ws + 4194304);    // 32 MB over kb+vfrag (gemm2->gemm3)
    float*          ffn_p0 = rec_p0;                            // reuse after ln1
    float*          ffn_p1 = rec_p1;
    float* outp = (float*)d_out;

    prep_q_kernel<<<2048, 256, 0, stream>>>(src, pos, qb);
    prep_kv_kernel<<<512, 256, 0, stream>>>(match, pos, kb, vfrag);
    transpose_all_kernel<<<5120, 256, 0, stream>>>(Wagg, W1, W2, WaggT, W1T, W2T);

    attn_kernel<<<1024, 256, 0, stream>>>(qb, kb, vfrag, mask, op0, op1, mlb);
    combine_kernel<<<4096, 256, 0, stream>>>(op0, op1, mlb, att);

    // rec = att @ Wagg + bagg   (split-K x2: K=1024 -> 2x512)
    gemm_bt_kernel<64, 128, 0, 0, 2><<<dim3(2, 128, 2), 256, 0, stream>>>(
        att, WaggT, bagg, rec_p0, rec_p1, nullptr, B_SZ * N_SEQ, C_DIM, K_HEADS * C_DIM);
    ln1_kernel<<<2048, 256, 0, stream>>>(src, rec_p0, rec_p1, g1, be1, rec1b);
    // hid = relu(rec1 @ W1 + b1)
    gemm_bt_kernel<128, 128, 1, 1, 1><<<dim3(16, 64), 256, 0, stream>>>(
        rec1b, W1T, b1, nullptr, nullptr, hid, N_SEQ * B_SZ, FF_DIM, C_DIM);
    // ffn = hid @ W2 + b2   (split-K x2: K=2048 -> 2x1024)
    gemm_bt_kernel<64, 128, 0, 0, 2><<<dim3(2, 128, 2), 256, 0, stream>>>(
        hid, W2T, b2, ffn_p0, ffn_p1, nullptr, N_SEQ * B_SZ, C_DIM, FF_DIM);
    ln2_kernel<<<2048, 256, 0, stream>>>(rec1b, ffn_p0, ffn_p1, g2, be2, outp);
}

// Round 12
// 160.594 us; speedup vs baseline: 1.5479x; 1.5479x over previous
//
#include <hip/hip_runtime.h>

#define N_SEQ 1024
#define B_SZ 8
#define C_DIM 256
#define K_HEADS 4
#define FF_DIM 2048

typedef short s16x8 __attribute__((ext_vector_type(8)));
typedef float f32x4v __attribute__((ext_vector_type(4)));

#define GLOAD_LDS16(src, dst)                                                              \
    __builtin_amdgcn_global_load_lds((const __attribute__((address_space(1))) void*)(src), \
                                     (__attribute__((address_space(3))) void*)(dst), 16, 0, 0)

__device__ __forceinline__ unsigned short f2bf(float f) {
    unsigned u = __builtin_bit_cast(unsigned, f);
    u += 0x7FFFu + ((u >> 16) & 1u);
    return (unsigned short)(u >> 16);
}
__device__ __forceinline__ float bf2f(unsigned short h) {
    unsigned u = ((unsigned)h) << 16;
    return __builtin_bit_cast(float, u);
}

// ---------------- prep kernels ----------------

__global__ __launch_bounds__(256) void prep_q_kernel(const float* __restrict__ src,
                                                     const float* __restrict__ pos,
                                                     unsigned short* __restrict__ qb) {
    int t = blockIdx.x * 256 + threadIdx.x;
    int i4 = t * 4;
    float4 s = *reinterpret_cast<const float4*>(src + i4);
    float4 p = *reinterpret_cast<const float4*>(pos + i4);
    int n = i4 >> 11;
    int rem = i4 & 2047;
    int b = rem >> 8;
    int c = rem & 255;
    int out = (b * N_SEQ + n) * C_DIM + c;
    *reinterpret_cast<ushort4*>(qb + out) = make_ushort4(
        f2bf((s.x + p.x) * 0.0625f), f2bf((s.y + p.y) * 0.0625f),
        f2bf((s.z + p.z) * 0.0625f), f2bf((s.w + p.w) * 0.0625f));
}

// One block per (k,b,ntile of 64): writes kb row-major (+pos) and V in
// per-wave-linear fragment order: vfrag[pr][tile32][ct=16][lane=64][e=8].
__global__ __launch_bounds__(256) void prep_kv_kernel(const float* __restrict__ matched,
                                                      const float* __restrict__ pos,
                                                      unsigned short* __restrict__ kb,
                                                      unsigned short* __restrict__ vfrag) {
    __shared__ unsigned short Vl[64][256];
    int blk = blockIdx.x;
    int nt = blk & 15, pr = blk >> 4;          // pr = k*8+b
    int k = pr >> 3, b = pr & 7;
    int n0 = nt * 64;
    int t = threadIdx.x;
    int c4 = (t & 63) * 4;
#pragma unroll
    for (int r = 0; r < 16; r++) {
        int nl = (t >> 6) * 16 + r;
        int n = n0 + nl;
        size_t mi = ((size_t)(k * N_SEQ + n) * B_SZ + b) * C_DIM + c4;
        float4 m = *reinterpret_cast<const float4*>(matched + mi);
        float4 p = *reinterpret_cast<const float4*>(pos + ((size_t)n * B_SZ + b) * C_DIM + c4);
        *reinterpret_cast<ushort4*>(kb + ((size_t)pr * N_SEQ + n) * C_DIM + c4) =
            make_ushort4(f2bf(m.x + p.x), f2bf(m.y + p.y), f2bf(m.z + p.z), f2bf(m.w + p.w));
        *reinterpret_cast<ushort4*>(&Vl[nl][c4]) =
            make_ushort4(f2bf(m.x), f2bf(m.y), f2bf(m.z), f2bf(m.w));
    }
    __syncthreads();
#pragma unroll
    for (int h = 0; h < 2; h++) {
        unsigned short* tb = vfrag + ((size_t)(pr * 32 + nt * 2 + h)) * 8192;
#pragma unroll
        for (int g = 0; g < 4; g++) {
            int c2 = t + 256 * g;                // chunk index 0..1023
            int ct = c2 >> 6;
            int lane2 = c2 & 63;
            int l152 = lane2 & 15, lg2 = lane2 >> 4;
            s16x8 v;
#pragma unroll
            for (int e = 0; e < 8; e++)
                v[e] = (short)Vl[h * 32 + lg2 * 8 + e][ct * 16 + l152];
            *reinterpret_cast<s16x8*>(tb + (size_t)c2 * 8) = v;
        }
    }
}

// merged weight transposes: Wt[c*R+r] = bf16(W[r*Cn+c]); all R,Cn powers of 2
__global__ __launch_bounds__(256) void transpose_all_kernel(const float* __restrict__ Wagg,
                                                            const float* __restrict__ W1,
                                                            const float* __restrict__ W2,
                                                            unsigned short* __restrict__ WaggT,
                                                            unsigned short* __restrict__ W1T,
                                                            unsigned short* __restrict__ W2T) {
    int idx = blockIdx.x * 256 + threadIdx.x;
    if (idx < 262144) {                        // Wagg: R=1024, Cn=256
        int c = idx >> 10, r = idx & 1023;
        WaggT[idx] = f2bf(Wagg[(size_t)r * 256 + c]);
    } else if (idx < 786432) {                 // W1: R=256, Cn=2048
        int i = idx - 262144;
        int c = i >> 8, r = i & 255;
        W1T[i] = f2bf(W1[(size_t)r * 2048 + c]);
    } else {                                   // W2: R=2048, Cn=256
        int i = idx - 786432;
        int c = i >> 11, r = i & 2047;
        W2T[i] = f2bf(W2[(size_t)r * 256 + c]);
    }
}

// ---------------- flash attention (KV-split x2, cooperative ch-split PV) ----------------
// grid = 1024 blocks x 256 threads. Block = 64 q (4 waves) x half the KV range.
// Wave w: QK+softmax for q-tile w; PV for channel quarter of ALL 4 q-tiles.
// LDS 37.5 KB -> 4 blocks/CU (VGPR ~92 permits it without forcing spills).
__global__ __launch_bounds__(256, 2) void attn_kernel(const unsigned short* __restrict__ qb,
                                                      const unsigned short* __restrict__ kb,
                                                      const unsigned short* __restrict__ vfrag,
                                                      const float* __restrict__ mask,
                                                      unsigned short* __restrict__ op0,
                                                      unsigned short* __restrict__ op1,
                                                      float2* __restrict__ mlb) {
    __shared__ unsigned short Kl[2][8192];       // 32 KB: K tile, XOR-swizzled content
    __shared__ unsigned short Psh[4][16][40];    // 5 KB: P exchange (single buffer: barrier A
                                                 //   separates PV-reads(t) from publish(t+1))
    __shared__ float scl[4][17];                 // rescale factors
    __shared__ float lrex[4][17];                // final l exchange

    int bx = blockIdx.x;
    int b = bx & 7;                              // XCD owns one batch's mask/Q
    int r2 = bx >> 3;
    int half = r2 & 1;
    int kidx = (r2 >> 1) & 3;
    int qtb = r2 >> 3;                           // 0..15 (64-q tiles)
    int pr = kidx * 8 + b;

    int tid = threadIdx.x, wid = tid >> 6, lane = tid & 63;
    int l15 = lane & 15, lg = lane >> 4;
    int q0 = qtb * 64 + wid * 16;                // wave's own q-tile base
    int kvh = half * 512;

    // Q fragments (wave's own 16 q)
    s16x8 qf[8];
    const unsigned short* qrow = qb + ((size_t)(b * N_SEQ + q0 + l15)) * C_DIM + lg * 8;
#pragma unroll
    for (int cc = 0; cc < 8; cc++) qf[cc] = *reinterpret_cast<const s16x8*>(qrow + cc * 32);

    f32x4v oacc[16];
#pragma unroll
    for (int i = 0; i < 16; i++) oacc[i] = (f32x4v){0.f, 0.f, 0.f, 0.f};
    float mrun = -3e38f, lrun = 0.f;

    const unsigned short* kbp = kb + ((size_t)pr * N_SEQ + kvh) * C_DIM;
    const unsigned short* vfp = vfrag + ((size_t)(pr * 32 + half * 16)) * 8192 + lane * 8;
    const float* mrow = mask + ((size_t)b * N_SEQ + q0 + l15) * N_SEQ + kvh;

    auto stage_k = [&](int kv0, unsigned short* buf) {
#pragma unroll
        for (int i = 0; i < 4; i++) {
            int ch = (wid * 4 + i) * 64 + lane;
            int r = ch >> 5;
            int ce = ((ch & 31) * 8) ^ ((r & 7) << 3);
            GLOAD_LDS16(kbp + (size_t)(kv0 + r) * C_DIM + ce, &buf[(wid * 4 + i) * 512]);
        }
    };

    // prologue
    stage_k(0, &Kl[0][0]);
    f32x4v mc0 = *reinterpret_cast<const f32x4v*>(mrow + lg * 4);
    f32x4v mc1 = *reinterpret_cast<const f32x4v*>(mrow + 16 + lg * 4);

    int swz = (l15 & 7) << 3;
    for (int t = 0; t < 16; t++) {
        int cur = t & 1;
        int kv0 = t * 32;
        __syncthreads();                         // (A) K[t] ready; Psh free (PV(t-1) done)
        if (t + 1 < 16) stage_k(kv0 + 32, &Kl[cur ^ 1][0]);

        // V fragments for this wave's channel quarter (4 coalesced 1KB loads, L2)
        const unsigned short* vsrc = vfp + (size_t)t * 8192;
        s16x8 vreg[4];
#pragma unroll
        for (int c = 0; c < 4; c++)
            vreg[c] = *reinterpret_cast<const s16x8*>(vsrc + (wid * 4 + c) * 512);

        // S^T = K Q^T (own q-tile)
        f32x4v s0 = {0.f, 0.f, 0.f, 0.f}, s1 = {0.f, 0.f, 0.f, 0.f};
        const unsigned short* KlB = &Kl[cur][0];
        __builtin_amdgcn_s_setprio(1);
#pragma unroll
        for (int cc = 0; cc < 8; cc++) {
            s16x8 k0 = *reinterpret_cast<const s16x8*>(KlB + l15 * 256 + ((cc * 32 + lg * 8) ^ swz));
            s16x8 k1 = *reinterpret_cast<const s16x8*>(KlB + (16 + l15) * 256 + ((cc * 32 + lg * 8) ^ swz));
            s0 = __builtin_amdgcn_mfma_f32_16x16x32_bf16(k0, qf[cc], s0, 0, 0, 0);
            s1 = __builtin_amdgcn_mfma_f32_16x16x32_bf16(k1, qf[cc], s1, 0, 0, 0);
        }
        __builtin_amdgcn_s_setprio(0);
#pragma unroll
        for (int jj = 0; jj < 4; jj++) { s0[jj] += mc0[jj]; s1[jj] += mc1[jj]; }
        if (t + 1 < 16) {
            mc0 = *reinterpret_cast<const f32x4v*>(mrow + kv0 + 32 + lg * 4);
            mc1 = *reinterpret_cast<const f32x4v*>(mrow + kv0 + 48 + lg * 4);
        }

        // online softmax over kv (in-lane 8 + xor 16/32)
        float pm = fmaxf(fmaxf(fmaxf(s0[0], s0[1]), fmaxf(s0[2], s0[3])),
                         fmaxf(fmaxf(s1[0], s1[1]), fmaxf(s1[2], s1[3])));
        pm = fmaxf(pm, __shfl_xor(pm, 16));
        pm = fmaxf(pm, __shfl_xor(pm, 32));
        float sc = 1.0f;
        if (__any(pm > mrun + 8.f)) {            // defer-max
            float mn = fmaxf(mrun, pm);
            sc = __expf(mrun - mn);
            mrun = mn;
        }
        float p0[4], p1[4];
#pragma unroll
        for (int jj = 0; jj < 4; jj++) {
            p0[jj] = __expf(s0[jj] - mrun);
            p1[jj] = __expf(s1[jj] - mrun);
        }
        float ps = (p0[0] + p0[1]) + (p0[2] + p0[3]) + (p1[0] + p1[1]) + (p1[2] + p1[3]);
        ps += __shfl_xor(ps, 16);
        ps += __shfl_xor(ps, 32);
        lrun = lrun * sc + ps;

        // publish P (A-fragment layout) + rescale factor
        *reinterpret_cast<ushort4*>(&Psh[wid][l15][lg * 4]) =
            make_ushort4(f2bf(p0[0]), f2bf(p0[1]), f2bf(p0[2]), f2bf(p0[3]));
        *reinterpret_cast<ushort4*>(&Psh[wid][l15][16 + lg * 4]) =
            make_ushort4(f2bf(p1[0]), f2bf(p1[1]), f2bf(p1[2]), f2bf(p1[3]));
        if (lane < 16) scl[wid][lane] = sc;
        __syncthreads();                         // (B) P + sc visible

        // PV: this wave's 64 channels x all 4 q-tiles
        __builtin_amdgcn_s_setprio(1);
#pragma unroll
        for (int j = 0; j < 4; j++) {
            float scj = scl[j][l15];
            s16x8 pf = *reinterpret_cast<const s16x8*>(&Psh[j][l15][lg * 8]);
            if (__any(scj != 1.0f)) {            // wave-uniform: rescale only when needed
#pragma unroll
                for (int c = 0; c < 4; c++)
#pragma unroll
                    for (int jj = 0; jj < 4; jj++) oacc[j * 4 + c][jj] *= scj;
            }
#pragma unroll
            for (int c = 0; c < 4; c++) {
                int idx = j * 4 + c;
                oacc[idx] = __builtin_amdgcn_mfma_f32_16x16x32_bf16(vreg[c], pf, oacc[idx], 0, 0, 0);
            }
        }
        __builtin_amdgcn_s_setprio(0);
    }

    // epilogue: exchange l, normalize, write partial O + (m,l)
    if (lane < 16) lrex[wid][lane] = lrun;
    __syncthreads();
    unsigned short* Op = half ? op1 : op0;
#pragma unroll
    for (int j = 0; j < 4; j++) {
        float invj = 1.0f / lrex[j][l15];
#pragma unroll
        for (int c = 0; c < 4; c++) {
            int idx = j * 4 + c;
            size_t orow = ((size_t)(b * N_SEQ + qtb * 64 + j * 16 + l15)) * (K_HEADS * C_DIM)
                          + kidx * C_DIM + wid * 64 + c * 16 + lg * 4;
            *reinterpret_cast<ushort4*>(Op + orow) =
                make_ushort4(f2bf(oacc[idx][0] * invj), f2bf(oacc[idx][1] * invj),
                             f2bf(oacc[idx][2] * invj), f2bf(oacc[idx][3] * invj));
        }
    }
    if (lg == 0)
        mlb[((size_t)(half * 4 + kidx) * 8 + b) * N_SEQ + q0 + l15] = make_float2(mrun, lrun);
}

// ---------------- combine two KV-half partials ----------------
__global__ __launch_bounds__(256) void combine_kernel(const unsigned short* __restrict__ op0,
                                                      const unsigned short* __restrict__ op1,
                                                      const float2* __restrict__ mlb,
                                                      unsigned short* __restrict__ att) {
    int t = blockIdx.x * 256 + threadIdx.x;
    int kidx = (t >> 5) & 3;
    int bn = t >> 7;
    int n = bn & 1023, b = bn >> 10;
    float2 e0 = mlb[((size_t)kidx * 8 + b) * N_SEQ + n];
    float2 e1 = mlb[((size_t)(4 + kidx) * 8 + b) * N_SEQ + n];
    float M = fmaxf(e0.x, e1.x);
    float w0 = e0.y * __expf(e0.x - M);
    float w1 = e1.y * __expf(e1.x - M);
    float r = 1.0f / (w0 + w1);
    w0 *= r;
    w1 *= r;
    s16x8 a = *reinterpret_cast<const s16x8*>(op0 + (size_t)t * 8);
    s16x8 c = *reinterpret_cast<const s16x8*>(op1 + (size_t)t * 8);
    s16x8 o;
#pragma unroll
    for (int i = 0; i < 8; i++)
        o[i] = (short)f2bf(w0 * bf2f((unsigned short)a[i]) + w1 * bf2f((unsigned short)c[i]));
    *reinterpret_cast<s16x8*>(att + (size_t)t * 8) = o;
}

// ---------------- GEMM: C = A(MxK) * Bt(NxK)^T + bias, optional split-K ----------------
template <int BM, int BN, int RELU, int OUTBF, int SPLITK>
__global__ __launch_bounds__(256) void gemm_bt_kernel(const unsigned short* __restrict__ A,
                                                      const unsigned short* __restrict__ Bt,
                                                      const float* __restrict__ bias,
                                                      float* __restrict__ Cf0,
                                                      float* __restrict__ Cf1,
                                                      unsigned short* __restrict__ Cb,
                                                      int M, int Nn, int Kd) {
    constexpr int WAVES_N = (BM == 128) ? 2 : 4;
    constexpr int WN = BN / WAVES_N;
    constexpr int NT = WN / 16;
    constexpr int TILE = (BM + BN) * 64;
    constexpr int CALLS = (BM + BN) / 32;
    __shared__ unsigned short Sl[2][TILE];
    int tm0 = blockIdx.y * BM, tn0 = blockIdx.x * BN;
    int kz = (SPLITK == 2) ? blockIdx.z : 0;
    int kbase = kz * (Kd / SPLITK);
    int tid = threadIdx.x, wid = tid >> 6, lane = tid & 63;
    int l15 = lane & 15, lg = lane >> 4;
    int wm = (wid / WAVES_N) * 64, wn = (wid % WAVES_N) * WN;

    f32x4v acc[4][NT];
#pragma unroll
    for (int i = 0; i < 4; i++)
#pragma unroll
        for (int j = 0; j < NT; j++) acc[i][j] = (f32x4v){0.f, 0.f, 0.f, 0.f};

    auto stage = [&](int k0, unsigned short* buf) {
#pragma unroll
        for (int i = 0; i < CALLS; i++) {
            int chb = (i * 4 + wid) * 64;
            int ch = chb + lane;
            const unsigned short* src;
            if (chb < BM * 8) {
                int r = ch >> 3;
                int c8 = ((ch & 7) * 8) ^ ((r & 7) << 3);
                src = A + (size_t)(tm0 + r) * Kd + k0 + c8;
            } else {
                int ch2 = ch - BM * 8;
                int r = ch2 >> 3;
                int c8 = ((ch2 & 7) * 8) ^ ((r & 7) << 3);
                src = Bt + (size_t)(tn0 + r) * Kd + k0 + c8;
            }
            GLOAD_LDS16(src, buf + chb * 8);
        }
    };

    stage(kbase, &Sl[0][0]);
    int nk = (Kd / SPLITK) >> 6;
    int swz = (l15 & 7) << 3;
    for (int kt = 0; kt < nk; kt++) {
        int cur = kt & 1;
        __syncthreads();
        if (kt + 1 < nk) stage(kbase + (kt + 1) * 64, &Sl[cur ^ 1][0]);
        const unsigned short* SA = &Sl[cur][0];
        const unsigned short* SB = SA + BM * 64;
        s16x8 af[4][2], bf[NT][2];
#pragma unroll
        for (int mt = 0; mt < 4; mt++)
#pragma unroll
            for (int h = 0; h < 2; h++)
                af[mt][h] = *reinterpret_cast<const s16x8*>(
                    SA + (wm + mt * 16 + l15) * 64 + ((h * 32 + lg * 8) ^ swz));
#pragma unroll
        for (int nt = 0; nt < NT; nt++)
#pragma unroll
            for (int h = 0; h < 2; h++)
                bf[nt][h] = *reinterpret_cast<const s16x8*>(
                    SB + (wn + nt * 16 + l15) * 64 + ((h * 32 + lg * 8) ^ swz));
        __builtin_amdgcn_s_setprio(1);
#pragma unroll
        for (int mt = 0; mt < 4; mt++)
#pragma unroll
            for (int nt = 0; nt < NT; nt++) {
                acc[mt][nt] = __builtin_amdgcn_mfma_f32_16x16x32_bf16(af[mt][0], bf[nt][0], acc[mt][nt], 0, 0, 0);
                acc[mt][nt] = __builtin_amdgcn_mfma_f32_16x16x32_bf16(af[mt][1], bf[nt][1], acc[mt][nt], 0, 0, 0);
            }
        __builtin_amdgcn_s_setprio(0);
    }

    float* Cf = (SPLITK == 2 && kz) ? Cf1 : Cf0;
#pragma unroll
    for (int mt = 0; mt < 4; mt++) {
#pragma unroll
        for (int nt = 0; nt < NT; nt++) {
#pragma unroll
            for (int j = 0; j < 4; j++) {
                int row = tm0 + wm + mt * 16 + lg * 4 + j;
                int col = tn0 + wn + nt * 16 + l15;
                float bv = (SPLITK == 2 && kz) ? 0.f : bias[col];
                float v = acc[mt][nt][j] + bv;
                if (RELU) v = fmaxf(v, 0.f);
                if (OUTBF) Cb[(size_t)row * Nn + col] = f2bf(v);
                else       Cf[(size_t)row * Nn + col] = v;
            }
        }
    }
}

// ---------------- fused residual + LayerNorm ----------------
__global__ __launch_bounds__(256) void ln1_kernel(const float* __restrict__ src,
                                                  const float* __restrict__ p0,
                                                  const float* __restrict__ p1,
                                                  const float* __restrict__ g,
                                                  const float* __restrict__ be,
                                                  unsigned short* __restrict__ outb) {
    int r = blockIdx.x * 4 + (threadIdx.x >> 6);
    int lane = threadIdx.x & 63;
    int n = r >> 3, b = r & 7;
    int c = lane * 4;
    size_t tb_ = ((size_t)(b * N_SEQ + n)) * C_DIM + c;
    float4 xs = *reinterpret_cast<const float4*>(src + (size_t)r * C_DIM + c);
    float4 xa = *reinterpret_cast<const float4*>(p0 + tb_);
    float4 xb = *reinterpret_cast<const float4*>(p1 + tb_);
    float x[4] = {xs.x + xa.x + xb.x, xs.y + xa.y + xb.y,
                  xs.z + xa.z + xb.z, xs.w + xa.w + xb.w};
    float s = x[0] + x[1] + x[2] + x[3];
    float q = x[0] * x[0] + x[1] * x[1] + x[2] * x[2] + x[3] * x[3];
#pragma unroll
    for (int d = 1; d < 64; d <<= 1) {
        s += __shfl_xor(s, d);
        q += __shfl_xor(q, d);
    }
    float mean = s * (1.f / 256.f);
    float var = q * (1.f / 256.f) - mean * mean;
    float rstd = rsqrtf(var + 1e-5f);
    float4 gv = *reinterpret_cast<const float4*>(g + c);
    float4 bv = *reinterpret_cast<const float4*>(be + c);
    *reinterpret_cast<ushort4*>(outb + (size_t)r * C_DIM + c) = make_ushort4(
        f2bf((x[0] - mean) * rstd * gv.x + bv.x), f2bf((x[1] - mean) * rstd * gv.y + bv.y),
        f2bf((x[2] - mean) * rstd * gv.z + bv.z), f2bf((x[3] - mean) * rstd * gv.w + bv.w));
}

__global__ __launch_bounds__(256) void ln2_kernel(const unsigned short* __restrict__ rec1b,
                                                  const float* __restrict__ p0,
                                                  const float* __restrict__ p1,
                                                  const float* __restrict__ g,
                                                  const float* __restrict__ be,
                                                  float* __restrict__ out) {
    int r = blockIdx.x * 4 + (threadIdx.x >> 6);
    int lane = threadIdx.x & 63;
    int c = lane * 4;
    size_t base = (size_t)r * C_DIM + c;
    ushort4 xr = *reinterpret_cast<const ushort4*>(rec1b + base);
    float4 xa = *reinterpret_cast<const float4*>(p0 + base);
    float4 xb = *reinterpret_cast<const float4*>(p1 + base);
    float x[4] = {bf2f(xr.x) + xa.x + xb.x, bf2f(xr.y) + xa.y + xb.y,
                  bf2f(xr.z) + xa.z + xb.z, bf2f(xr.w) + xa.w + xb.w};
    float s = x[0] + x[1] + x[2] + x[3];
    float q = x[0] * x[0] + x[1] * x[1] + x[2] * x[2] + x[3] * x[3];
#pragma unroll
    for (int d = 1; d < 64; d <<= 1) {
        s += __shfl_xor(s, d);
        q += __shfl_xor(q, d);
    }
    float mean = s * (1.f / 256.f);
    float var = q * (1.f / 256.f) - mean * mean;
    float rstd = rsqrtf(var + 1e-5f);
    float4 gv = *reinterpret_cast<const float4*>(g + c);
    float4 bv = *reinterpret_cast<const float4*>(be + c);
    *reinterpret_cast<float4*>(out + base) = make_float4(
        (x[0] - mean) * rstd * gv.x + bv.x,
        (x[1] - mean) * rstd * gv.y + bv.y,
        (x[2] - mean) * rstd * gv.z + bv.z,
        (x[3] - mean) * rstd * gv.w + bv.w);
}

// ---------------- launch ----------------

extern "C" void kernel_launch(void* const* d_in, const int* in_sizes, int n_in,
                              void* d_out, int out_size, void* d_ws, size_t ws_size,
                              hipStream_t stream) {
    const float* src   = (const float*)d_in[0];
    const float* match = (const float*)d_in[1];
    const float* pos   = (const float*)d_in[2];
    const float* mask  = (const float*)d_in[3];
    const float* Wagg  = (const float*)d_in[4];
    const float* bagg  = (const float*)d_in[5];
    const float* W1    = (const float*)d_in[6];
    const float* b1    = (const float*)d_in[7];
    const float* W2    = (const float*)d_in[8];
    const float* b2    = (const float*)d_in[9];
    const float* g1    = (const float*)d_in[10];
    const float* be1   = (const float*)d_in[11];
    const float* g2    = (const float*)d_in[12];
    const float* be2   = (const float*)d_in[13];

    char* ws = (char*)d_ws;
    unsigned short* qb    = (unsigned short*)(ws + 0);          //  4 MB (prep->attn)
    unsigned short* kb    = (unsigned short*)(ws + 4194304);    // 16 MB (prep->attn)
    unsigned short* vfrag = (unsigned short*)(ws + 20971520);   // 16 MB (prep->attn)
    unsigned short* att   = (unsigned short*)(ws + 37748736);   // 16 MB (attn->gemm1); = op0
    unsigned short* WaggT = (unsigned short*)(ws + 54525952);   // 0.5 MB
    unsigned short* W1T   = (unsigned short*)(ws + 55050240);   // 1 MB
    unsigned short* W2T   = (unsigned short*)(ws + 56098816);   // 1 MB
    float*          rec_p0 = (float*)(ws + 57147392);           // 8 MB (gemm1->ln1)
    float*          rec_p1 = (float*)(ws + 65536000);           // 8 MB (gemm1->ln1)
    // attention-phase aliases (dead regions during attn):
    unsigned short* op0   = att;                                // 16 MB partial half0 (combined in-place)
    unsigned short* op1   = (unsigned short*)(ws + 57147392);   // 16 MB partial half1 (over rec_p0+p1)
    float2*         mlb   = (float2*)(ws + 73924608);           // 512 KB
    // post-attn aliases:
    unsigned short* rec1b = (unsigned short*)(ws + 0);          // 4 MB over qb (ln1->ln2)
    unsigned short* hid   = (unsigned short*)(ws + 4194304);    // 32 MB over kb+vfrag (gemm2->gemm3)
    float*          ffn_p0 = rec_p0;                            // reuse after ln1
    float*          ffn_p1 = rec_p1;
    float* outp = (float*)d_out;

    prep_q_kernel<<<2048, 256, 0, stream>>>(src, pos, qb);
    prep_kv_kernel<<<512, 256, 0, stream>>>(match, pos, kb, vfrag);
    transpose_all_kernel<<<5120, 256, 0, stream>>>(Wagg, W1, W2, WaggT, W1T, W2T);

    attn_kernel<<<1024, 256, 0, stream>>>(qb, kb, vfrag, mask, op0, op1, mlb);
    combine_kernel<<<4096, 256, 0, stream>>>(op0, op1, mlb, att);

    // rec = att @ Wagg + bagg   (split-K x2: K=1024 -> 2x512)
    gemm_bt_kernel<64, 128, 0, 0, 2><<<dim3(2, 128, 2), 256, 0, stream>>>(
        att, WaggT, bagg, rec_p0, rec_p1, nullptr, B_SZ * N_SEQ, C_DIM, K_HEADS * C_DIM);
    ln1_kernel<<<2048, 256, 0, stream>>>(src, rec_p0, rec_p1, g1, be1, rec1b);
    // hid = relu(rec1 @ W1 + b1)
    gemm_bt_kernel<128, 128, 1, 1, 1><<<dim3(16, 64), 256, 0, stream>>>(
        rec1b, W1T, b1, nullptr, nullptr, hid, N_SEQ * B_SZ, FF_DIM, C_DIM);
    // ffn = hid @ W2 + b2   (split-K x2: K=2048 -> 2x1024)
    gemm_bt_kernel<64, 128, 0, 0, 2><<<dim3(2, 128, 2), 256, 0, stream>>>(
        hid, W2T, b2, ffn_p0, ffn_p1, nullptr, N_SEQ * B_SZ, C_DIM, FF_DIM);
    ln2_kernel<<<2048, 256, 0, stream>>>(rec1b, ffn_p0, ffn_p1, g2, be2, outp);
}

// Round 13
// 139.934 us; speedup vs baseline: 1.7764x; 1.1476x over previous
//
#include <hip/hip_runtime.h>

#define N_SEQ 1024
#define B_SZ 8
#define C_DIM 256
#define K_HEADS 4
#define FF_DIM 2048

typedef short s16x8 __attribute__((ext_vector_type(8)));
typedef float f32x4v __attribute__((ext_vector_type(4)));

#define GLOAD_LDS16(src, dst)                                                              \
    __builtin_amdgcn_global_load_lds((const __attribute__((address_space(1))) void*)(src), \
                                     (__attribute__((address_space(3))) void*)(dst), 16, 0, 0)

__device__ __forceinline__ unsigned short f2bf(float f) {
    unsigned u = __builtin_bit_cast(unsigned, f);
    u += 0x7FFFu + ((u >> 16) & 1u);
    return (unsigned short)(u >> 16);
}
__device__ __forceinline__ float bf2f(unsigned short h) {
    unsigned u = ((unsigned)h) << 16;
    return __builtin_bit_cast(float, u);
}

// ---------------- prep kernels ----------------

__global__ __launch_bounds__(256) void prep_q_kernel(const float* __restrict__ src,
                                                     const float* __restrict__ pos,
                                                     unsigned short* __restrict__ qb) {
    int t = blockIdx.x * 256 + threadIdx.x;
    int i4 = t * 4;
    float4 s = *reinterpret_cast<const float4*>(src + i4);
    float4 p = *reinterpret_cast<const float4*>(pos + i4);
    int n = i4 >> 11;
    int rem = i4 & 2047;
    int b = rem >> 8;
    int c = rem & 255;
    int out = (b * N_SEQ + n) * C_DIM + c;
    *reinterpret_cast<ushort4*>(qb + out) = make_ushort4(
        f2bf((s.x + p.x) * 0.0625f), f2bf((s.y + p.y) * 0.0625f),
        f2bf((s.z + p.z) * 0.0625f), f2bf((s.w + p.w) * 0.0625f));
}

// One block per (k,b,ntile of 64): writes kb row-major (+pos) and V in
// per-wave-linear fragment order: vfrag[pr][tile32][ct=16][lane=64][e=8].
__global__ __launch_bounds__(256) void prep_kv_kernel(const float* __restrict__ matched,
                                                      const float* __restrict__ pos,
                                                      unsigned short* __restrict__ kb,
                                                      unsigned short* __restrict__ vfrag) {
    __shared__ unsigned short Vl[64][256];
    int blk = blockIdx.x;
    int nt = blk & 15, pr = blk >> 4;          // pr = k*8+b
    int k = pr >> 3, b = pr & 7;
    int n0 = nt * 64;
    int t = threadIdx.x;
    int c4 = (t & 63) * 4;
#pragma unroll
    for (int r = 0; r < 16; r++) {
        int nl = (t >> 6) * 16 + r;
        int n = n0 + nl;
        size_t mi = ((size_t)(k * N_SEQ + n) * B_SZ + b) * C_DIM + c4;
        float4 m = *reinterpret_cast<const float4*>(matched + mi);
        float4 p = *reinterpret_cast<const float4*>(pos + ((size_t)n * B_SZ + b) * C_DIM + c4);
        *reinterpret_cast<ushort4*>(kb + ((size_t)pr * N_SEQ + n) * C_DIM + c4) =
            make_ushort4(f2bf(m.x + p.x), f2bf(m.y + p.y), f2bf(m.z + p.z), f2bf(m.w + p.w));
        *reinterpret_cast<ushort4*>(&Vl[nl][c4]) =
            make_ushort4(f2bf(m.x), f2bf(m.y), f2bf(m.z), f2bf(m.w));
    }
    __syncthreads();
#pragma unroll
    for (int h = 0; h < 2; h++) {
        unsigned short* tb = vfrag + ((size_t)(pr * 32 + nt * 2 + h)) * 8192;
#pragma unroll
        for (int g = 0; g < 4; g++) {
            int c2 = t + 256 * g;                // chunk index 0..1023
            int ct = c2 >> 6;
            int lane2 = c2 & 63;
            int l152 = lane2 & 15, lg2 = lane2 >> 4;
            s16x8 v;
#pragma unroll
            for (int e = 0; e < 8; e++)
                v[e] = (short)Vl[h * 32 + lg2 * 8 + e][ct * 16 + l152];
            *reinterpret_cast<s16x8*>(tb + (size_t)c2 * 8) = v;
        }
    }
}

// merged weight transposes: Wt[c*R+r] = bf16(W[r*Cn+c]); all R,Cn powers of 2
__global__ __launch_bounds__(256) void transpose_all_kernel(const float* __restrict__ Wagg,
                                                            const float* __restrict__ W1,
                                                            const float* __restrict__ W2,
                                                            unsigned short* __restrict__ WaggT,
                                                            unsigned short* __restrict__ W1T,
                                                            unsigned short* __restrict__ W2T) {
    int idx = blockIdx.x * 256 + threadIdx.x;
    if (idx < 262144) {                        // Wagg: R=1024, Cn=256
        int c = idx >> 10, r = idx & 1023;
        WaggT[idx] = f2bf(Wagg[(size_t)r * 256 + c]);
    } else if (idx < 786432) {                 // W1: R=256, Cn=2048
        int i = idx - 262144;
        int c = i >> 8, r = i & 255;
        W1T[i] = f2bf(W1[(size_t)r * 2048 + c]);
    } else {                                   // W2: R=2048, Cn=256
        int i = idx - 786432;
        int c = i >> 11, r = i & 2047;
        W2T[i] = f2bf(W2[(size_t)r * 256 + c]);
    }
}

// ---------------- flash attention (single-pass, KVBLK=64, coop ch-split PV) ----------------
// grid = 512 blocks x 256 threads. Block = 64 q (4 waves), full KV range, 16 iters of 64 kv.
// Wave w: QK+softmax for q-tile w; PV for channel quarter of ALL 4 q-tiles (P via LDS).
__global__ __launch_bounds__(256, 2) void attn_kernel(const unsigned short* __restrict__ qb,
                                                      const unsigned short* __restrict__ kb,
                                                      const unsigned short* __restrict__ vfrag,
                                                      const float* __restrict__ mask,
                                                      unsigned short* __restrict__ att) {
    __shared__ unsigned short Kl[2][16384];      // 64 KB: K tile 64x256, XOR-swizzled content
    __shared__ unsigned short Psh[4][16][72];    // 9 KB: P exchange (single buffer; barrier A
                                                 //   separates PV-reads(t-1) from publish(t))
    __shared__ float scl[4][17];                 // rescale factors
    __shared__ float lrex[4][17];                // final l exchange

    int bx = blockIdx.x;
    int b = bx & 7;                              // XCD owns one batch's mask/Q
    int r2 = bx >> 3;
    int kidx = r2 & 3;
    int qtb = r2 >> 2;                           // 0..15 (64-q tiles)
    int pr = kidx * 8 + b;

    int tid = threadIdx.x, wid = tid >> 6, lane = tid & 63;
    int l15 = lane & 15, lg = lane >> 4;
    int q0 = qtb * 64 + wid * 16;                // wave's own q-tile base

    // Q fragments (wave's own 16 q)
    s16x8 qf[8];
    const unsigned short* qrow = qb + ((size_t)(b * N_SEQ + q0 + l15)) * C_DIM + lg * 8;
#pragma unroll
    for (int cc = 0; cc < 8; cc++) qf[cc] = *reinterpret_cast<const s16x8*>(qrow + cc * 32);

    f32x4v oacc[16];
#pragma unroll
    for (int i = 0; i < 16; i++) oacc[i] = (f32x4v){0.f, 0.f, 0.f, 0.f};
    float mrun = -3e38f, lrun = 0.f;

    const unsigned short* kbp = kb + (size_t)pr * N_SEQ * C_DIM;
    const unsigned short* vfp = vfrag + (size_t)pr * 32 * 8192 + lane * 8;
    const float* mrow = mask + ((size_t)b * N_SEQ + q0 + l15) * N_SEQ;

    // stage 64x256 K tile: 2048 16B-chunks, 8 per thread
    auto stage_k = [&](int kv0, unsigned short* buf) {
#pragma unroll
        for (int i = 0; i < 8; i++) {
            int ch = (wid * 8 + i) * 64 + lane;
            int r = ch >> 5;
            int ce = ((ch & 31) * 8) ^ ((r & 7) << 3);
            GLOAD_LDS16(kbp + (size_t)(kv0 + r) * C_DIM + ce, &buf[(wid * 8 + i) * 512]);
        }
    };

    // prologue
    stage_k(0, &Kl[0][0]);
    f32x4v mc0 = *reinterpret_cast<const f32x4v*>(mrow + lg * 4);
    f32x4v mc1 = *reinterpret_cast<const f32x4v*>(mrow + 16 + lg * 4);
    f32x4v mc2 = *reinterpret_cast<const f32x4v*>(mrow + 32 + lg * 4);
    f32x4v mc3 = *reinterpret_cast<const f32x4v*>(mrow + 48 + lg * 4);

    int swz = (l15 & 7) << 3;
    for (int t = 0; t < 16; t++) {
        int cur = t & 1;
        int kv0 = t * 64;
        __syncthreads();                         // (A) K[t] ready; Psh free (PV(t-1) done)
        if (t + 1 < 16) stage_k(kv0 + 64, &Kl[cur ^ 1][0]);

        // V fragments for this wave's channel quarter (two 32-kv subtiles; L2)
        const unsigned short* vsrc0 = vfp + (size_t)(2 * t) * 8192;
        const unsigned short* vsrc1 = vfp + (size_t)(2 * t + 1) * 8192;
        s16x8 vreg0[4], vreg1[4];
#pragma unroll
        for (int c = 0; c < 4; c++) {
            vreg0[c] = *reinterpret_cast<const s16x8*>(vsrc0 + (wid * 4 + c) * 512);
            vreg1[c] = *reinterpret_cast<const s16x8*>(vsrc1 + (wid * 4 + c) * 512);
        }

        // S^T = K Q^T (own q-tile): 4 kv-row groups
        f32x4v s0 = {0.f, 0.f, 0.f, 0.f}, s1 = {0.f, 0.f, 0.f, 0.f};
        f32x4v s2 = {0.f, 0.f, 0.f, 0.f}, s3 = {0.f, 0.f, 0.f, 0.f};
        const unsigned short* KlB = &Kl[cur][0];
        __builtin_amdgcn_s_setprio(1);
#pragma unroll
        for (int cc = 0; cc < 8; cc++) {
            int co = (cc * 32 + lg * 8) ^ swz;
            s16x8 k0 = *reinterpret_cast<const s16x8*>(KlB + l15 * 256 + co);
            s16x8 k1 = *reinterpret_cast<const s16x8*>(KlB + (16 + l15) * 256 + co);
            s16x8 k2 = *reinterpret_cast<const s16x8*>(KlB + (32 + l15) * 256 + co);
            s16x8 k3 = *reinterpret_cast<const s16x8*>(KlB + (48 + l15) * 256 + co);
            s0 = __builtin_amdgcn_mfma_f32_16x16x32_bf16(k0, qf[cc], s0, 0, 0, 0);
            s1 = __builtin_amdgcn_mfma_f32_16x16x32_bf16(k1, qf[cc], s1, 0, 0, 0);
            s2 = __builtin_amdgcn_mfma_f32_16x16x32_bf16(k2, qf[cc], s2, 0, 0, 0);
            s3 = __builtin_amdgcn_mfma_f32_16x16x32_bf16(k3, qf[cc], s3, 0, 0, 0);
        }
        __builtin_amdgcn_s_setprio(0);
#pragma unroll
        for (int jj = 0; jj < 4; jj++) {
            s0[jj] += mc0[jj];
            s1[jj] += mc1[jj];
            s2[jj] += mc2[jj];
            s3[jj] += mc3[jj];
        }
        if (t + 1 < 16) {
            mc0 = *reinterpret_cast<const f32x4v*>(mrow + kv0 + 64 + lg * 4);
            mc1 = *reinterpret_cast<const f32x4v*>(mrow + kv0 + 80 + lg * 4);
            mc2 = *reinterpret_cast<const f32x4v*>(mrow + kv0 + 96 + lg * 4);
            mc3 = *reinterpret_cast<const f32x4v*>(mrow + kv0 + 112 + lg * 4);
        }

        // online softmax over 16 in-lane kv + xor 16/32
        float pm = fmaxf(fmaxf(fmaxf(s0[0], s0[1]), fmaxf(s0[2], s0[3])),
                         fmaxf(fmaxf(s1[0], s1[1]), fmaxf(s1[2], s1[3])));
        float pm2 = fmaxf(fmaxf(fmaxf(s2[0], s2[1]), fmaxf(s2[2], s2[3])),
                          fmaxf(fmaxf(s3[0], s3[1]), fmaxf(s3[2], s3[3])));
        pm = fmaxf(pm, pm2);
        pm = fmaxf(pm, __shfl_xor(pm, 16));
        pm = fmaxf(pm, __shfl_xor(pm, 32));
        float sc = 1.0f;
        if (__any(pm > mrun + 8.f)) {            // defer-max
            float mn = fmaxf(mrun, pm);
            sc = __expf(mrun - mn);
            mrun = mn;
        }
        float p0[4], p1[4], p2[4], p3[4];
#pragma unroll
        for (int jj = 0; jj < 4; jj++) {
            p0[jj] = __expf(s0[jj] - mrun);
            p1[jj] = __expf(s1[jj] - mrun);
            p2[jj] = __expf(s2[jj] - mrun);
            p3[jj] = __expf(s3[jj] - mrun);
        }
        float ps = ((p0[0] + p0[1]) + (p0[2] + p0[3])) + ((p1[0] + p1[1]) + (p1[2] + p1[3]))
                 + ((p2[0] + p2[1]) + (p2[2] + p2[3])) + ((p3[0] + p3[1]) + (p3[2] + p3[3]));
        ps += __shfl_xor(ps, 16);
        ps += __shfl_xor(ps, 32);
        lrun = lrun * sc + ps;

        // publish P (A-fragment layout) + rescale factor
        *reinterpret_cast<ushort4*>(&Psh[wid][l15][lg * 4]) =
            make_ushort4(f2bf(p0[0]), f2bf(p0[1]), f2bf(p0[2]), f2bf(p0[3]));
        *reinterpret_cast<ushort4*>(&Psh[wid][l15][16 + lg * 4]) =
            make_ushort4(f2bf(p1[0]), f2bf(p1[1]), f2bf(p1[2]), f2bf(p1[3]));
        *reinterpret_cast<ushort4*>(&Psh[wid][l15][32 + lg * 4]) =
            make_ushort4(f2bf(p2[0]), f2bf(p2[1]), f2bf(p2[2]), f2bf(p2[3]));
        *reinterpret_cast<ushort4*>(&Psh[wid][l15][48 + lg * 4]) =
            make_ushort4(f2bf(p3[0]), f2bf(p3[1]), f2bf(p3[2]), f2bf(p3[3]));
        if (lane < 16) scl[wid][lane] = sc;
        __syncthreads();                         // (B) P + sc visible

        // PV: this wave's 64 channels x all 4 q-tiles, 2 kv-subtiles each
        __builtin_amdgcn_s_setprio(1);
#pragma unroll
        for (int j = 0; j < 4; j++) {
            float scj = scl[j][l15];
            s16x8 pf0 = *reinterpret_cast<const s16x8*>(&Psh[j][l15][lg * 8]);
            s16x8 pf1 = *reinterpret_cast<const s16x8*>(&Psh[j][l15][32 + lg * 8]);
            if (__any(scj != 1.0f)) {            // wave-uniform: rescale only when needed
#pragma unroll
                for (int c = 0; c < 4; c++)
#pragma unroll
                    for (int jj = 0; jj < 4; jj++) oacc[j * 4 + c][jj] *= scj;
            }
#pragma unroll
            for (int c = 0; c < 4; c++) {
                int idx = j * 4 + c;
                oacc[idx] = __builtin_amdgcn_mfma_f32_16x16x32_bf16(vreg0[c], pf0, oacc[idx], 0, 0, 0);
                oacc[idx] = __builtin_amdgcn_mfma_f32_16x16x32_bf16(vreg1[c], pf1, oacc[idx], 0, 0, 0);
            }
        }
        __builtin_amdgcn_s_setprio(0);
    }

    // epilogue: exchange l, normalize, write O
    if (lane < 16) lrex[wid][lane] = lrun;
    __syncthreads();
#pragma unroll
    for (int j = 0; j < 4; j++) {
        float invj = 1.0f / lrex[j][l15];
#pragma unroll
        for (int c = 0; c < 4; c++) {
            int idx = j * 4 + c;
            size_t orow = ((size_t)(b * N_SEQ + qtb * 64 + j * 16 + l15)) * (K_HEADS * C_DIM)
                          + kidx * C_DIM + wid * 64 + c * 16 + lg * 4;
            *reinterpret_cast<ushort4*>(att + orow) =
                make_ushort4(f2bf(oacc[idx][0] * invj), f2bf(oacc[idx][1] * invj),
                             f2bf(oacc[idx][2] * invj), f2bf(oacc[idx][3] * invj));
        }
    }
}

// ---------------- GEMM: C = A(MxK) * Bt(NxK)^T + bias, optional split-K ----------------
template <int BM, int BN, int RELU, int OUTBF, int SPLITK>
__global__ __launch_bounds__(256) void gemm_bt_kernel(const unsigned short* __restrict__ A,
                                                      const unsigned short* __restrict__ Bt,
                                                      const float* __restrict__ bias,
                                                      float* __restrict__ Cf0,
                                                      float* __restrict__ Cf1,
                                                      unsigned short* __restrict__ Cb,
                                                      int M, int Nn, int Kd) {
    constexpr int WAVES_N = (BM == 128) ? 2 : 4;
    constexpr int WN = BN / WAVES_N;
    constexpr int NT = WN / 16;
    constexpr int TILE = (BM + BN) * 64;
    constexpr int CALLS = (BM + BN) / 32;
    __shared__ unsigned short Sl[2][TILE];
    int tm0 = blockIdx.y * BM, tn0 = blockIdx.x * BN;
    int kz = (SPLITK == 2) ? blockIdx.z : 0;
    int kbase = kz * (Kd / SPLITK);
    int tid = threadIdx.x, wid = tid >> 6, lane = tid & 63;
    int l15 = lane & 15, lg = lane >> 4;
    int wm = (wid / WAVES_N) * 64, wn = (wid % WAVES_N) * WN;

    f32x4v acc[4][NT];
#pragma unroll
    for (int i = 0; i < 4; i++)
#pragma unroll
        for (int j = 0; j < NT; j++) acc[i][j] = (f32x4v){0.f, 0.f, 0.f, 0.f};

    auto stage = [&](int k0, unsigned short* buf) {
#pragma unroll
        for (int i = 0; i < CALLS; i++) {
            int chb = (i * 4 + wid) * 64;
            int ch = chb + lane;
            const unsigned short* src;
            if (chb < BM * 8) {
                int r = ch >> 3;
                int c8 = ((ch & 7) * 8) ^ ((r & 7) << 3);
                src = A + (size_t)(tm0 + r) * Kd + k0 + c8;
            } else {
                int ch2 = ch - BM * 8;
                int r = ch2 >> 3;
                int c8 = ((ch2 & 7) * 8) ^ ((r & 7) << 3);
                src = Bt + (size_t)(tn0 + r) * Kd + k0 + c8;
            }
            GLOAD_LDS16(src, buf + chb * 8);
        }
    };

    stage(kbase, &Sl[0][0]);
    int nk = (Kd / SPLITK) >> 6;
    int swz = (l15 & 7) << 3;
    for (int kt = 0; kt < nk; kt++) {
        int cur = kt & 1;
        __syncthreads();
        if (kt + 1 < nk) stage(kbase + (kt + 1) * 64, &Sl[cur ^ 1][0]);
        const unsigned short* SA = &Sl[cur][0];
        const unsigned short* SB = SA + BM * 64;
        s16x8 af[4][2], bf[NT][2];
#pragma unroll
        for (int mt = 0; mt < 4; mt++)
#pragma unroll
            for (int h = 0; h < 2; h++)
                af[mt][h] = *reinterpret_cast<const s16x8*>(
                    SA + (wm + mt * 16 + l15) * 64 + ((h * 32 + lg * 8) ^ swz));
#pragma unroll
        for (int nt = 0; nt < NT; nt++)
#pragma unroll
            for (int h = 0; h < 2; h++)
                bf[nt][h] = *reinterpret_cast<const s16x8*>(
                    SB + (wn + nt * 16 + l15) * 64 + ((h * 32 + lg * 8) ^ swz));
        __builtin_amdgcn_s_setprio(1);
#pragma unroll
        for (int mt = 0; mt < 4; mt++)
#pragma unroll
            for (int nt = 0; nt < NT; nt++) {
                acc[mt][nt] = __builtin_amdgcn_mfma_f32_16x16x32_bf16(af[mt][0], bf[nt][0], acc[mt][nt], 0, 0, 0);
                acc[mt][nt] = __builtin_amdgcn_mfma_f32_16x16x32_bf16(af[mt][1], bf[nt][1], acc[mt][nt], 0, 0, 0);
            }
        __builtin_amdgcn_s_setprio(0);
    }

    float* Cf = (SPLITK == 2 && kz) ? Cf1 : Cf0;
#pragma unroll
    for (int mt = 0; mt < 4; mt++) {
#pragma unroll
        for (int nt = 0; nt < NT; nt++) {
#pragma unroll
            for (int j = 0; j < 4; j++) {
                int row = tm0 + wm + mt * 16 + lg * 4 + j;
                int col = tn0 + wn + nt * 16 + l15;
                float bv = (SPLITK == 2 && kz) ? 0.f : bias[col];
                float v = acc[mt][nt][j] + bv;
                if (RELU) v = fmaxf(v, 0.f);
                if (OUTBF) Cb[(size_t)row * Nn + col] = f2bf(v);
                else       Cf[(size_t)row * Nn + col] = v;
            }
        }
    }
}

// ---------------- fused residual + LayerNorm ----------------
__global__ __launch_bounds__(256) void ln1_kernel(const float* __restrict__ src,
                                                  const float* __restrict__ p0,
                                                  const float* __restrict__ p1,
                                                  const float* __restrict__ g,
                                                  const float* __restrict__ be,
                                                  unsigned short* __restrict__ outb) {
    int r = blockIdx.x * 4 + (threadIdx.x >> 6);
    int lane = threadIdx.x & 63;
    int n = r >> 3, b = r & 7;
    int c = lane * 4;
    size_t tb_ = ((size_t)(b * N_SEQ + n)) * C_DIM + c;
    float4 xs = *reinterpret_cast<const float4*>(src + (size_t)r * C_DIM + c);
    float4 xa = *reinterpret_cast<const float4*>(p0 + tb_);
    float4 xb = *reinterpret_cast<const float4*>(p1 + tb_);
    float x[4] = {xs.x + xa.x + xb.x, xs.y + xa.y + xb.y,
                  xs.z + xa.z + xb.z, xs.w + xa.w + xb.w};
    float s = x[0] + x[1] + x[2] + x[3];
    float q = x[0] * x[0] + x[1] * x[1] + x[2] * x[2] + x[3] * x[3];
#pragma unroll
    for (int d = 1; d < 64; d <<= 1) {
        s += __shfl_xor(s, d);
        q += __shfl_xor(q, d);
    }
    float mean = s * (1.f / 256.f);
    float var = q * (1.f / 256.f) - mean * mean;
    float rstd = rsqrtf(var + 1e-5f);
    float4 gv = *reinterpret_cast<const float4*>(g + c);
    float4 bv = *reinterpret_cast<const float4*>(be + c);
    *reinterpret_cast<ushort4*>(outb + (size_t)r * C_DIM + c) = make_ushort4(
        f2bf((x[0] - mean) * rstd * gv.x + bv.x), f2bf((x[1] - mean) * rstd * gv.y + bv.y),
        f2bf((x[2] - mean) * rstd * gv.z + bv.z), f2bf((x[3] - mean) * rstd * gv.w + bv.w));
}

__global__ __launch_bounds__(256) void ln2_kernel(const unsigned short* __restrict__ rec1b,
                                                  const float* __restrict__ p0,
                                                  const float* __restrict__ p1,
                                                  const float* __restrict__ g,
                                                  const float* __restrict__ be,
                                                  float* __restrict__ out) {
    int r = blockIdx.x * 4 + (threadIdx.x >> 6);
    int lane = threadIdx.x & 63;
    int c = lane * 4;
    size_t base = (size_t)r * C_DIM + c;
    ushort4 xr = *reinterpret_cast<const ushort4*>(rec1b + base);
    float4 xa = *reinterpret_cast<const float4*>(p0 + base);
    float4 xb = *reinterpret_cast<const float4*>(p1 + base);
    float x[4] = {bf2f(xr.x) + xa.x + xb.x, bf2f(xr.y) + xa.y + xb.y,
                  bf2f(xr.z) + xa.z + xb.z, bf2f(xr.w) + xa.w + xb.w};
    float s = x[0] + x[1] + x[2] + x[3];
    float q = x[0] * x[0] + x[1] * x[1] + x[2] * x[2] + x[3] * x[3];
#pragma unroll
    for (int d = 1; d < 64; d <<= 1) {
        s += __shfl_xor(s, d);
        q += __shfl_xor(q, d);
    }
    float mean = s * (1.f / 256.f);
    float var = q * (1.f / 256.f) - mean * mean;
    float rstd = rsqrtf(var + 1e-5f);
    float4 gv = *reinterpret_cast<const float4*>(g + c);
    float4 bv = *reinterpret_cast<const float4*>(be + c);
    *reinterpret_cast<float4*>(out + base) = make_float4(
        (x[0] - mean) * rstd * gv.x + bv.x,
        (x[1] - mean) * rstd * gv.y + bv.y,
        (x[2] - mean) * rstd * gv.z + bv.z,
        (x[3] - mean) * rstd * gv.w + bv.w);
}

// ---------------- launch ----------------

extern "C" void kernel_launch(void* const* d_in, const int* in_sizes, int n_in,
                              void* d_out, int out_size, void* d_ws, size_t ws_size,
                              hipStream_t stream) {
    const float* src   = (const float*)d_in[0];
    const float* match = (const float*)d_in[1];
    const float* pos   = (const float*)d_in[2];
    const float* mask  = (const float*)d_in[3];
    const float* Wagg  = (const float*)d_in[4];
    const float* bagg  = (const float*)d_in[5];
    const float* W1    = (const float*)d_in[6];
    const float* b1    = (const float*)d_in[7];
    const float* W2    = (const float*)d_in[8];
    const float* b2    = (const float*)d_in[9];
    const float* g1    = (const float*)d_in[10];
    const float* be1   = (const float*)d_in[11];
    const float* g2    = (const float*)d_in[12];
    const float* be2   = (const float*)d_in[13];

    char* ws = (char*)d_ws;
    unsigned short* qb    = (unsigned short*)(ws + 0);          //  4 MB (prep->attn)
    unsigned short* kb    = (unsigned short*)(ws + 4194304);    // 16 MB (prep->attn)
    unsigned short* vfrag = (unsigned short*)(ws + 20971520);   // 16 MB (prep->attn)
    unsigned short* att   = (unsigned short*)(ws + 37748736);   // 16 MB (attn->gemm1)
    unsigned short* WaggT = (unsigned short*)(ws + 54525952);   // 0.5 MB
    unsigned short* W1T   = (unsigned short*)(ws + 55050240);   // 1 MB
    unsigned short* W2T   = (unsigned short*)(ws + 56098816);   // 1 MB
    float*          rec_p0 = (float*)(ws + 57147392);           // 8 MB (gemm1->ln1)
    float*          rec_p1 = (float*)(ws + 65536000);           // 8 MB (gemm1->ln1)
    // post-attn aliases:
    unsigned short* rec1b = (unsigned short*)(ws + 0);          // 4 MB over qb (ln1->ln2)
    unsigned short* hid   = (unsigned short*)(ws + 4194304);    // 32 MB over kb+vfrag (gemm2->gemm3)
    float*          ffn_p0 = rec_p0;                            // reuse after ln1
    float*          ffn_p1 = rec_p1;
    float* outp = (float*)d_out;

    prep_q_kernel<<<2048, 256, 0, stream>>>(src, pos, qb);
    prep_kv_kernel<<<512, 256, 0, stream>>>(match, pos, kb, vfrag);
    transpose_all_kernel<<<5120, 256, 0, stream>>>(Wagg, W1, W2, WaggT, W1T, W2T);

    attn_kernel<<<512, 256, 0, stream>>>(qb, kb, vfrag, mask, att);

    // rec = att @ Wagg + bagg   (split-K x2: K=1024 -> 2x512)
    gemm_bt_kernel<64, 128, 0, 0, 2><<<dim3(2, 128, 2), 256, 0, stream>>>(
        att, WaggT, bagg, rec_p0, rec_p1, nullptr, B_SZ * N_SEQ, C_DIM, K_HEADS * C_DIM);
    ln1_kernel<<<2048, 256, 0, stream>>>(src, rec_p0, rec_p1, g1, be1, rec1b);
    // hid = relu(rec1 @ W1 + b1)
    gemm_bt_kernel<128, 128, 1, 1, 1><<<dim3(16, 64), 256, 0, stream>>>(
        rec1b, W1T, b1, nullptr, nullptr, hid, N_SEQ * B_SZ, FF_DIM, C_DIM);
    // ffn = hid @ W2 + b2   (split-K x2: K=2048 -> 2x1024)
    gemm_bt_kernel<64, 128, 0, 0, 2><<<dim3(2, 128, 2), 256, 0, stream>>>(
        hid, W2T, b2, ffn_p0, ffn_p1, nullptr, N_SEQ * B_SZ, C_DIM, FF_DIM);
    ln2_kernel<<<2048, 256, 0, stream>>>(rec1b, ffn_p0, ffn_p1, g2, be2, outp);
}

// Round 14
// 135.376 us; speedup vs baseline: 1.8362x; 1.0337x over previous
//
#include <hip/hip_runtime.h>

#define N_SEQ 1024
#define B_SZ 8
#define C_DIM 256
#define K_HEADS 4
#define FF_DIM 2048

typedef short s16x8 __attribute__((ext_vector_type(8)));
typedef float f32x4v __attribute__((ext_vector_type(4)));

#define GLOAD_LDS16(src, dst)                                                              \
    __builtin_amdgcn_global_load_lds((const __attribute__((address_space(1))) void*)(src), \
                                     (__attribute__((address_space(3))) void*)(dst), 16, 0, 0)

__device__ __forceinline__ unsigned short f2bf(float f) {
    unsigned u = __builtin_bit_cast(unsigned, f);
    u += 0x7FFFu + ((u >> 16) & 1u);
    return (unsigned short)(u >> 16);
}
__device__ __forceinline__ float bf2f(unsigned short h) {
    unsigned u = ((unsigned)h) << 16;
    return __builtin_bit_cast(float, u);
}

// ---------------- merged prep kernel ----------------
// blocks [0,512): kb (+pos, bf16) and vfrag fragment tiles
// blocks [512,2560): qb (pre-scaled bf16, (b,n,c) layout)
// blocks [2560,7680): weight transposes to bf16
__global__ __launch_bounds__(256) void prep_all_kernel(const float* __restrict__ src,
                                                       const float* __restrict__ pos,
                                                       const float* __restrict__ matched,
                                                       const float* __restrict__ Wagg,
                                                       const float* __restrict__ W1,
                                                       const float* __restrict__ W2,
                                                       unsigned short* __restrict__ qb,
                                                       unsigned short* __restrict__ kb,
                                                       unsigned short* __restrict__ vfrag,
                                                       unsigned short* __restrict__ WaggT,
                                                       unsigned short* __restrict__ W1T,
                                                       unsigned short* __restrict__ W2T) {
    __shared__ unsigned short Vl[64][256];
    int blk = blockIdx.x;
    int t = threadIdx.x;
    if (blk < 512) {
        // ---- prep_kv ----
        int nt = blk & 15, pr = blk >> 4;          // pr = k*8+b
        int k = pr >> 3, b = pr & 7;
        int n0 = nt * 64;
        int c4 = (t & 63) * 4;
#pragma unroll
        for (int r = 0; r < 16; r++) {
            int nl = (t >> 6) * 16 + r;
            int n = n0 + nl;
            size_t mi = ((size_t)(k * N_SEQ + n) * B_SZ + b) * C_DIM + c4;
            float4 m = *reinterpret_cast<const float4*>(matched + mi);
            float4 p = *reinterpret_cast<const float4*>(pos + ((size_t)n * B_SZ + b) * C_DIM + c4);
            *reinterpret_cast<ushort4*>(kb + ((size_t)pr * N_SEQ + n) * C_DIM + c4) =
                make_ushort4(f2bf(m.x + p.x), f2bf(m.y + p.y), f2bf(m.z + p.z), f2bf(m.w + p.w));
            *reinterpret_cast<ushort4*>(&Vl[nl][c4]) =
                make_ushort4(f2bf(m.x), f2bf(m.y), f2bf(m.z), f2bf(m.w));
        }
        __syncthreads();
#pragma unroll
        for (int h = 0; h < 2; h++) {
            unsigned short* tb = vfrag + ((size_t)(pr * 32 + nt * 2 + h)) * 8192;
#pragma unroll
            for (int g = 0; g < 4; g++) {
                int c2 = t + 256 * g;                // chunk index 0..1023
                int ct = c2 >> 6;
                int lane2 = c2 & 63;
                int l152 = lane2 & 15, lg2 = lane2 >> 4;
                s16x8 v;
#pragma unroll
                for (int e = 0; e < 8; e++)
                    v[e] = (short)Vl[h * 32 + lg2 * 8 + e][ct * 16 + l152];
                *reinterpret_cast<s16x8*>(tb + (size_t)c2 * 8) = v;
            }
        }
    } else if (blk < 2560) {
        // ---- prep_q ----
        int tt = (blk - 512) * 256 + t;
        int i4 = tt * 4;
        float4 s = *reinterpret_cast<const float4*>(src + i4);
        float4 p = *reinterpret_cast<const float4*>(pos + i4);
        int n = i4 >> 11;
        int rem = i4 & 2047;
        int b = rem >> 8;
        int c = rem & 255;
        int out = (b * N_SEQ + n) * C_DIM + c;
        *reinterpret_cast<ushort4*>(qb + out) = make_ushort4(
            f2bf((s.x + p.x) * 0.0625f), f2bf((s.y + p.y) * 0.0625f),
            f2bf((s.z + p.z) * 0.0625f), f2bf((s.w + p.w) * 0.0625f));
    } else {
        // ---- weight transposes ----
        int idx = (blk - 2560) * 256 + t;
        if (idx < 262144) {                        // Wagg: R=1024, Cn=256
            int c = idx >> 10, r = idx & 1023;
            WaggT[idx] = f2bf(Wagg[(size_t)r * 256 + c]);
        } else if (idx < 786432) {                 // W1: R=256, Cn=2048
            int i = idx - 262144;
            int c = i >> 8, r = i & 255;
            W1T[i] = f2bf(W1[(size_t)r * 2048 + c]);
        } else {                                   // W2: R=2048, Cn=256
            int i = idx - 786432;
            int c = i >> 11, r = i & 2047;
            W2T[i] = f2bf(W2[(size_t)r * 256 + c]);
        }
    }
}

// ---------------- flash attention (single-pass, KVBLK=64, coop ch-split PV) ----------------
// grid = 512 blocks x 256 threads. Block = 64 q (4 waves), full KV range, 16 iters of 64 kv.
// Wave w: QK+softmax for q-tile w; PV for channel quarter of ALL 4 q-tiles (P via LDS).
__global__ __launch_bounds__(256, 2) void attn_kernel(const unsigned short* __restrict__ qb,
                                                      const unsigned short* __restrict__ kb,
                                                      const unsigned short* __restrict__ vfrag,
                                                      const float* __restrict__ mask,
                                                      unsigned short* __restrict__ att) {
    __shared__ unsigned short Kl[2][16384];      // 64 KB: K tile 64x256, XOR-swizzled content
    __shared__ unsigned short Psh[4][16][72];    // 9 KB: P exchange (single buffer; barrier A
                                                 //   separates PV-reads(t-1) from publish(t))
    __shared__ float scl[4][17];                 // rescale factors
    __shared__ float lrex[4][17];                // final l exchange

    int bx = blockIdx.x;
    int b = bx & 7;                              // XCD owns one batch's mask/Q
    int r2 = bx >> 3;
    int kidx = r2 & 3;
    int qtb = r2 >> 2;                           // 0..15 (64-q tiles)
    int pr = kidx * 8 + b;

    int tid = threadIdx.x, wid = tid >> 6, lane = tid & 63;
    int l15 = lane & 15, lg = lane >> 4;
    int q0 = qtb * 64 + wid * 16;                // wave's own q-tile base

    // Q fragments (wave's own 16 q)
    s16x8 qf[8];
    const unsigned short* qrow = qb + ((size_t)(b * N_SEQ + q0 + l15)) * C_DIM + lg * 8;
#pragma unroll
    for (int cc = 0; cc < 8; cc++) qf[cc] = *reinterpret_cast<const s16x8*>(qrow + cc * 32);

    f32x4v oacc[16];
#pragma unroll
    for (int i = 0; i < 16; i++) oacc[i] = (f32x4v){0.f, 0.f, 0.f, 0.f};
    float mrun = -3e38f, lrun = 0.f;

    const unsigned short* kbp = kb + (size_t)pr * N_SEQ * C_DIM;
    const unsigned short* vfp = vfrag + (size_t)pr * 32 * 8192 + lane * 8;
    const float* mrow = mask + ((size_t)b * N_SEQ + q0 + l15) * N_SEQ;

    // stage 64x256 K tile: 2048 16B-chunks, 8 per thread
    auto stage_k = [&](int kv0, unsigned short* buf) {
#pragma unroll
        for (int i = 0; i < 8; i++) {
            int ch = (wid * 8 + i) * 64 + lane;
            int r = ch >> 5;
            int ce = ((ch & 31) * 8) ^ ((r & 7) << 3);
            GLOAD_LDS16(kbp + (size_t)(kv0 + r) * C_DIM + ce, &buf[(wid * 8 + i) * 512]);
        }
    };

    // prologue
    stage_k(0, &Kl[0][0]);
    f32x4v mc0 = *reinterpret_cast<const f32x4v*>(mrow + lg * 4);
    f32x4v mc1 = *reinterpret_cast<const f32x4v*>(mrow + 16 + lg * 4);
    f32x4v mc2 = *reinterpret_cast<const f32x4v*>(mrow + 32 + lg * 4);
    f32x4v mc3 = *reinterpret_cast<const f32x4v*>(mrow + 48 + lg * 4);

    int swz = (l15 & 7) << 3;
    for (int t = 0; t < 16; t++) {
        int cur = t & 1;
        int kv0 = t * 64;
        __syncthreads();                         // (A) K[t] ready; Psh free (PV(t-1) done)
        if (t + 1 < 16) stage_k(kv0 + 64, &Kl[cur ^ 1][0]);

        // V fragments for this wave's channel quarter (two 32-kv subtiles; L2)
        const unsigned short* vsrc0 = vfp + (size_t)(2 * t) * 8192;
        const unsigned short* vsrc1 = vfp + (size_t)(2 * t + 1) * 8192;
        s16x8 vreg0[4], vreg1[4];
#pragma unroll
        for (int c = 0; c < 4; c++) {
            vreg0[c] = *reinterpret_cast<const s16x8*>(vsrc0 + (wid * 4 + c) * 512);
            vreg1[c] = *reinterpret_cast<const s16x8*>(vsrc1 + (wid * 4 + c) * 512);
        }

        // S^T = K Q^T (own q-tile): 4 kv-row groups
        f32x4v s0 = {0.f, 0.f, 0.f, 0.f}, s1 = {0.f, 0.f, 0.f, 0.f};
        f32x4v s2 = {0.f, 0.f, 0.f, 0.f}, s3 = {0.f, 0.f, 0.f, 0.f};
        const unsigned short* KlB = &Kl[cur][0];
        __builtin_amdgcn_s_setprio(1);
#pragma unroll
        for (int cc = 0; cc < 8; cc++) {
            int co = (cc * 32 + lg * 8) ^ swz;
            s16x8 k0 = *reinterpret_cast<const s16x8*>(KlB + l15 * 256 + co);
            s16x8 k1 = *reinterpret_cast<const s16x8*>(KlB + (16 + l15) * 256 + co);
            s16x8 k2 = *reinterpret_cast<const s16x8*>(KlB + (32 + l15) * 256 + co);
            s16x8 k3 = *reinterpret_cast<const s16x8*>(KlB + (48 + l15) * 256 + co);
            s0 = __builtin_amdgcn_mfma_f32_16x16x32_bf16(k0, qf[cc], s0, 0, 0, 0);
            s1 = __builtin_amdgcn_mfma_f32_16x16x32_bf16(k1, qf[cc], s1, 0, 0, 0);
            s2 = __builtin_amdgcn_mfma_f32_16x16x32_bf16(k2, qf[cc], s2, 0, 0, 0);
            s3 = __builtin_amdgcn_mfma_f32_16x16x32_bf16(k3, qf[cc], s3, 0, 0, 0);
        }
        __builtin_amdgcn_s_setprio(0);
#pragma unroll
        for (int jj = 0; jj < 4; jj++) {
            s0[jj] += mc0[jj];
            s1[jj] += mc1[jj];
            s2[jj] += mc2[jj];
            s3[jj] += mc3[jj];
        }
        if (t + 1 < 16) {
            mc0 = *reinterpret_cast<const f32x4v*>(mrow + kv0 + 64 + lg * 4);
            mc1 = *reinterpret_cast<const f32x4v*>(mrow + kv0 + 80 + lg * 4);
            mc2 = *reinterpret_cast<const f32x4v*>(mrow + kv0 + 96 + lg * 4);
            mc3 = *reinterpret_cast<const f32x4v*>(mrow + kv0 + 112 + lg * 4);
        }

        // online softmax over 16 in-lane kv + xor 16/32
        float pm = fmaxf(fmaxf(fmaxf(s0[0], s0[1]), fmaxf(s0[2], s0[3])),
                         fmaxf(fmaxf(s1[0], s1[1]), fmaxf(s1[2], s1[3])));
        float pm2 = fmaxf(fmaxf(fmaxf(s2[0], s2[1]), fmaxf(s2[2], s2[3])),
                          fmaxf(fmaxf(s3[0], s3[1]), fmaxf(s3[2], s3[3])));
        pm = fmaxf(pm, pm2);
        pm = fmaxf(pm, __shfl_xor(pm, 16));
        pm = fmaxf(pm, __shfl_xor(pm, 32));
        float sc = 1.0f;
        if (__any(pm > mrun + 8.f)) {            // defer-max
            float mn = fmaxf(mrun, pm);
            sc = __expf(mrun - mn);
            mrun = mn;
        }
        float p0[4], p1[4], p2[4], p3[4];
#pragma unroll
        for (int jj = 0; jj < 4; jj++) {
            p0[jj] = __expf(s0[jj] - mrun);
            p1[jj] = __expf(s1[jj] - mrun);
            p2[jj] = __expf(s2[jj] - mrun);
            p3[jj] = __expf(s3[jj] - mrun);
        }
        float ps = ((p0[0] + p0[1]) + (p0[2] + p0[3])) + ((p1[0] + p1[1]) + (p1[2] + p1[3]))
                 + ((p2[0] + p2[1]) + (p2[2] + p2[3])) + ((p3[0] + p3[1]) + (p3[2] + p3[3]));
        ps += __shfl_xor(ps, 16);
        ps += __shfl_xor(ps, 32);
        lrun = lrun * sc + ps;

        // publish P (A-fragment layout) + rescale factor
        *reinterpret_cast<ushort4*>(&Psh[wid][l15][lg * 4]) =
            make_ushort4(f2bf(p0[0]), f2bf(p0[1]), f2bf(p0[2]), f2bf(p0[3]));
        *reinterpret_cast<ushort4*>(&Psh[wid][l15][16 + lg * 4]) =
            make_ushort4(f2bf(p1[0]), f2bf(p1[1]), f2bf(p1[2]), f2bf(p1[3]));
        *reinterpret_cast<ushort4*>(&Psh[wid][l15][32 + lg * 4]) =
            make_ushort4(f2bf(p2[0]), f2bf(p2[1]), f2bf(p2[2]), f2bf(p2[3]));
        *reinterpret_cast<ushort4*>(&Psh[wid][l15][48 + lg * 4]) =
            make_ushort4(f2bf(p3[0]), f2bf(p3[1]), f2bf(p3[2]), f2bf(p3[3]));
        if (lane < 16) scl[wid][lane] = sc;
        __syncthreads();                         // (B) P + sc visible

        // PV: this wave's 64 channels x all 4 q-tiles, 2 kv-subtiles each
        __builtin_amdgcn_s_setprio(1);
#pragma unroll
        for (int j = 0; j < 4; j++) {
            float scj = scl[j][l15];
            s16x8 pf0 = *reinterpret_cast<const s16x8*>(&Psh[j][l15][lg * 8]);
            s16x8 pf1 = *reinterpret_cast<const s16x8*>(&Psh[j][l15][32 + lg * 8]);
            if (__any(scj != 1.0f)) {            // wave-uniform: rescale only when needed
#pragma unroll
                for (int c = 0; c < 4; c++)
#pragma unroll
                    for (int jj = 0; jj < 4; jj++) oacc[j * 4 + c][jj] *= scj;
            }
#pragma unroll
            for (int c = 0; c < 4; c++) {
                int idx = j * 4 + c;
                oacc[idx] = __builtin_amdgcn_mfma_f32_16x16x32_bf16(vreg0[c], pf0, oacc[idx], 0, 0, 0);
                oacc[idx] = __builtin_amdgcn_mfma_f32_16x16x32_bf16(vreg1[c], pf1, oacc[idx], 0, 0, 0);
            }
        }
        __builtin_amdgcn_s_setprio(0);
    }

    // epilogue: exchange l, normalize, write O
    if (lane < 16) lrex[wid][lane] = lrun;
    __syncthreads();
#pragma unroll
    for (int j = 0; j < 4; j++) {
        float invj = 1.0f / lrex[j][l15];
#pragma unroll
        for (int c = 0; c < 4; c++) {
            int idx = j * 4 + c;
            size_t orow = ((size_t)(b * N_SEQ + qtb * 64 + j * 16 + l15)) * (K_HEADS * C_DIM)
                          + kidx * C_DIM + wid * 64 + c * 16 + lg * 4;
            *reinterpret_cast<ushort4*>(att + orow) =
                make_ushort4(f2bf(oacc[idx][0] * invj), f2bf(oacc[idx][1] * invj),
                             f2bf(oacc[idx][2] * invj), f2bf(oacc[idx][3] * invj));
        }
    }
}

// ---------------- GEMM: C = A(MxK) * Bt(NxK)^T + bias, optional split-K ----------------
template <int BM, int BN, int RELU, int OUTBF, int SPLITK>
__global__ __launch_bounds__(256) void gemm_bt_kernel(const unsigned short* __restrict__ A,
                                                      const unsigned short* __restrict__ Bt,
                                                      const float* __restrict__ bias,
                                                      float* __restrict__ Cf0,
                                                      float* __restrict__ Cf1,
                                                      unsigned short* __restrict__ Cb,
                                                      int M, int Nn, int Kd) {
    constexpr int WAVES_N = (BM == 128) ? 2 : 4;
    constexpr int WN = BN / WAVES_N;
    constexpr int NT = WN / 16;
    constexpr int TILE = (BM + BN) * 64;
    constexpr int CALLS = (BM + BN) / 32;
    __shared__ unsigned short Sl[2][TILE];
    int tm0 = blockIdx.y * BM, tn0 = blockIdx.x * BN;
    int kz = (SPLITK == 2) ? blockIdx.z : 0;
    int kbase = kz * (Kd / SPLITK);
    int tid = threadIdx.x, wid = tid >> 6, lane = tid & 63;
    int l15 = lane & 15, lg = lane >> 4;
    int wm = (wid / WAVES_N) * 64, wn = (wid % WAVES_N) * WN;

    f32x4v acc[4][NT];
#pragma unroll
    for (int i = 0; i < 4; i++)
#pragma unroll
        for (int j = 0; j < NT; j++) acc[i][j] = (f32x4v){0.f, 0.f, 0.f, 0.f};

    auto stage = [&](int k0, unsigned short* buf) {
#pragma unroll
        for (int i = 0; i < CALLS; i++) {
            int chb = (i * 4 + wid) * 64;
            int ch = chb + lane;
            const unsigned short* src;
            if (chb < BM * 8) {
                int r = ch >> 3;
                int c8 = ((ch & 7) * 8) ^ ((r & 7) << 3);
                src = A + (size_t)(tm0 + r) * Kd + k0 + c8;
            } else {
                int ch2 = ch - BM * 8;
                int r = ch2 >> 3;
                int c8 = ((ch2 & 7) * 8) ^ ((r & 7) << 3);
                src = Bt + (size_t)(tn0 + r) * Kd + k0 + c8;
            }
            GLOAD_LDS16(src, buf + chb * 8);
        }
    };

    stage(kbase, &Sl[0][0]);
    int nk = (Kd / SPLITK) >> 6;
    int swz = (l15 & 7) << 3;
    for (int kt = 0; kt < nk; kt++) {
        int cur = kt & 1;
        __syncthreads();
        if (kt + 1 < nk) stage(kbase + (kt + 1) * 64, &Sl[cur ^ 1][0]);
        const unsigned short* SA = &Sl[cur][0];
        const unsigned short* SB = SA + BM * 64;
        s16x8 af[4][2], bf[NT][2];
#pragma unroll
        for (int mt = 0; mt < 4; mt++)
#pragma unroll
            for (int h = 0; h < 2; h++)
                af[mt][h] = *reinterpret_cast<const s16x8*>(
                    SA + (wm + mt * 16 + l15) * 64 + ((h * 32 + lg * 8) ^ swz));
#pragma unroll
        for (int nt = 0; nt < NT; nt++)
#pragma unroll
            for (int h = 0; h < 2; h++)
                bf[nt][h] = *reinterpret_cast<const s16x8*>(
                    SB + (wn + nt * 16 + l15) * 64 + ((h * 32 + lg * 8) ^ swz));
        __builtin_amdgcn_s_setprio(1);
#pragma unroll
        for (int mt = 0; mt < 4; mt++)
#pragma unroll
            for (int nt = 0; nt < NT; nt++) {
                acc[mt][nt] = __builtin_amdgcn_mfma_f32_16x16x32_bf16(af[mt][0], bf[nt][0], acc[mt][nt], 0, 0, 0);
                acc[mt][nt] = __builtin_amdgcn_mfma_f32_16x16x32_bf16(af[mt][1], bf[nt][1], acc[mt][nt], 0, 0, 0);
            }
        __builtin_amdgcn_s_setprio(0);
    }

    float* Cf = (SPLITK == 2 && kz) ? Cf1 : Cf0;
#pragma unroll
    for (int mt = 0; mt < 4; mt++) {
#pragma unroll
        for (int nt = 0; nt < NT; nt++) {
#pragma unroll
            for (int j = 0; j < 4; j++) {
                int row = tm0 + wm + mt * 16 + lg * 4 + j;
                int col = tn0 + wn + nt * 16 + l15;
                float bv = (SPLITK == 2 && kz) ? 0.f : bias[col];
                float v = acc[mt][nt][j] + bv;
                if (RELU) v = fmaxf(v, 0.f);
                if (OUTBF) Cb[(size_t)row * Nn + col] = f2bf(v);
                else       Cf[(size_t)row * Nn + col] = v;
            }
        }
    }
}

// ---------------- fused residual + LayerNorm ----------------
__global__ __launch_bounds__(256) void ln1_kernel(const float* __restrict__ src,
                                                  const float* __restrict__ p0,
                                                  const float* __restrict__ p1,
                                                  const float* __restrict__ g,
                                                  const float* __restrict__ be,
                                                  unsigned short* __restrict__ outb) {
    int r = blockIdx.x * 4 + (threadIdx.x >> 6);
    int lane = threadIdx.x & 63;
    int n = r >> 3, b = r & 7;
    int c = lane * 4;
    size_t tb_ = ((size_t)(b * N_SEQ + n)) * C_DIM + c;
    float4 xs = *reinterpret_cast<const float4*>(src + (size_t)r * C_DIM + c);
    float4 xa = *reinterpret_cast<const float4*>(p0 + tb_);
    float4 xb = *reinterpret_cast<const float4*>(p1 + tb_);
    float x[4] = {xs.x + xa.x + xb.x, xs.y + xa.y + xb.y,
                  xs.z + xa.z + xb.z, xs.w + xa.w + xb.w};
    float s = x[0] + x[1] + x[2] + x[3];
    float q = x[0] * x[0] + x[1] * x[1] + x[2] * x[2] + x[3] * x[3];
#pragma unroll
    for (int d = 1; d < 64; d <<= 1) {
        s += __shfl_xor(s, d);
        q += __shfl_xor(q, d);
    }
    float mean = s * (1.f / 256.f);
    float var = q * (1.f / 256.f) - mean * mean;
    float rstd = rsqrtf(var + 1e-5f);
    float4 gv = *reinterpret_cast<const float4*>(g + c);
    float4 bv = *reinterpret_cast<const float4*>(be + c);
    *reinterpret_cast<ushort4*>(outb + (size_t)r * C_DIM + c) = make_ushort4(
        f2bf((x[0] - mean) * rstd * gv.x + bv.x), f2bf((x[1] - mean) * rstd * gv.y + bv.y),
        f2bf((x[2] - mean) * rstd * gv.z + bv.z), f2bf((x[3] - mean) * rstd * gv.w + bv.w));
}

__global__ __launch_bounds__(256) void ln2_kernel(const unsigned short* __restrict__ rec1b,
                                                  const float* __restrict__ p0,
                                                  const float* __restrict__ p1,
                                                  const float* __restrict__ g,
                                                  const float* __restrict__ be,
                                                  float* __restrict__ out) {
    int r = blockIdx.x * 4 + (threadIdx.x >> 6);
    int lane = threadIdx.x & 63;
    int c = lane * 4;
    size_t base = (size_t)r * C_DIM + c;
    ushort4 xr = *reinterpret_cast<const ushort4*>(rec1b + base);
    float4 xa = *reinterpret_cast<const float4*>(p0 + base);
    float4 xb = *reinterpret_cast<const float4*>(p1 + base);
    float x[4] = {bf2f(xr.x) + xa.x + xb.x, bf2f(xr.y) + xa.y + xb.y,
                  bf2f(xr.z) + xa.z + xb.z, bf2f(xr.w) + xa.w + xb.w};
    float s = x[0] + x[1] + x[2] + x[3];
    float q = x[0] * x[0] + x[1] * x[1] + x[2] * x[2] + x[3] * x[3];
#pragma unroll
    for (int d = 1; d < 64; d <<= 1) {
        s += __shfl_xor(s, d);
        q += __shfl_xor(q, d);
    }
    float mean = s * (1.f / 256.f);
    float var = q * (1.f / 256.f) - mean * mean;
    float rstd = rsqrtf(var + 1e-5f);
    float4 gv = *reinterpret_cast<const float4*>(g + c);
    float4 bv = *reinterpret_cast<const float4*>(be + c);
    *reinterpret_cast<float4*>(out + base) = make_float4(
        (x[0] - mean) * rstd * gv.x + bv.x,
        (x[1] - mean) * rstd * gv.y + bv.y,
        (x[2] - mean) * rstd * gv.z + bv.z,
        (x[3] - mean) * rstd * gv.w + bv.w);
}

// ---------------- launch ----------------

extern "C" void kernel_launch(void* const* d_in, const int* in_sizes, int n_in,
                              void* d_out, int out_size, void* d_ws, size_t ws_size,
                              hipStream_t stream) {
    const float* src   = (const float*)d_in[0];
    const float* match = (const float*)d_in[1];
    const float* pos   = (const float*)d_in[2];
    const float* mask  = (const float*)d_in[3];
    const float* Wagg  = (const float*)d_in[4];
    const float* bagg  = (const float*)d_in[5];
    const float* W1    = (const float*)d_in[6];
    const float* b1    = (const float*)d_in[7];
    const float* W2    = (const float*)d_in[8];
    const float* b2    = (const float*)d_in[9];
    const float* g1    = (const float*)d_in[10];
    const float* be1   = (const float*)d_in[11];
    const float* g2    = (const float*)d_in[12];
    const float* be2   = (const float*)d_in[13];

    char* ws = (char*)d_ws;
    unsigned short* qb    = (unsigned short*)(ws + 0);          //  4 MB (prep->attn)
    unsigned short* kb    = (unsigned short*)(ws + 4194304);    // 16 MB (prep->attn)
    unsigned short* vfrag = (unsigned short*)(ws + 20971520);   // 16 MB (prep->attn)
    unsigned short* att   = (unsigned short*)(ws + 37748736);   // 16 MB (attn->gemm1)
    unsigned short* WaggT = (unsigned short*)(ws + 54525952);   // 0.5 MB
    unsigned short* W1T   = (unsigned short*)(ws + 55050240);   // 1 MB
    unsigned short* W2T   = (unsigned short*)(ws + 56098816);   // 1 MB
    float*          rec_p0 = (float*)(ws + 57147392);           // 8 MB (gemm1->ln1)
    float*          rec_p1 = (float*)(ws + 65536000);           // 8 MB (gemm1->ln1)
    // post-attn aliases:
    unsigned short* rec1b = (unsigned short*)(ws + 0);          // 4 MB over qb (ln1->ln2)
    unsigned short* hid   = (unsigned short*)(ws + 4194304);    // 32 MB over kb+vfrag (gemm2->gemm3)
    float*          ffn_p0 = rec_p0;                            // reuse after ln1
    float*          ffn_p1 = rec_p1;
    float* outp = (float*)d_out;

    prep_all_kernel<<<7680, 256, 0, stream>>>(src, pos, match, Wagg, W1, W2,
                                              qb, kb, vfrag, WaggT, W1T, W2T);

    attn_kernel<<<512, 256, 0, stream>>>(qb, kb, vfrag, mask, att);

    // rec = att @ Wagg + bagg   (split-K x2: K=1024 -> 2x512)
    gemm_bt_kernel<64, 128, 0, 0, 2><<<dim3(2, 128, 2), 256, 0, stream>>>(
        att, WaggT, bagg, rec_p0, rec_p1, nullptr, B_SZ * N_SEQ, C_DIM, K_HEADS * C_DIM);
    ln1_kernel<<<2048, 256, 0, stream>>>(src, rec_p0, rec_p1, g1, be1, rec1b);
    // hid = relu(rec1 @ W1 + b1)   (BM=64 -> 3 blocks/CU, 2048 blocks)
    gemm_bt_kernel<64, 128, 1, 1, 1><<<dim3(16, 128), 256, 0, stream>>>(
        rec1b, W1T, b1, nullptr, nullptr, hid, N_SEQ * B_SZ, FF_DIM, C_DIM);
    // ffn = hid @ W2 + b2   (split-K x2: K=2048 -> 2x1024)
    gemm_bt_kernel<64, 128, 0, 0, 2><<<dim3(2, 128, 2), 256, 0, stream>>>(
        hid, W2T, b2, ffn_p0, ffn_p1, nullptr, N_SEQ * B_SZ, C_DIM, FF_DIM);
    ln2_kernel<<<2048, 256, 0, stream>>>(rec1b, ffn_p0, ffn_p1, g2, be2, outp);
}